// Round 1
// baseline (1049.490 us; speedup 1.0000x reference)
//
#include <hip/hip_runtime.h>
#include <hip/hip_bf16.h>

// Qwen3 MoE block: T=8192 tokens, H=1024, I=512, E=32, top-4.
// Fast path: router(+x->bf16) -> w->bf16 transpose -> scan/build ->
//   gateup GEMM (global_load_lds, swizzled) -> down GEMM -> gather.

#define T_TOK 8192
#define H_DIM 1024
#define I_DIM 512
#define E_NUM 32
#define K_TOP 4
#define NSLOT (T_TOK * K_TOP)

typedef __bf16 bf16_t;
typedef __bf16 bf16x8 __attribute__((ext_vector_type(8)));
typedef float floatx4 __attribute__((ext_vector_type(4)));

__device__ __forceinline__ void async_lds16(const void* g, void* l) {
  __builtin_amdgcn_global_load_lds(
      (const __attribute__((address_space(1))) void*)g,
      (__attribute__((address_space(3))) void*)l, 16, 0, 0);
}

// ---------------- Router: one block per token (also emits bf16 x) ----------
__global__ __launch_bounds__(256) void router_kernel(
    const float* __restrict__ x, const float* __restrict__ gate_w,
    int* __restrict__ counts, int* __restrict__ topk_idx,
    float* __restrict__ topk_wt, bf16_t* __restrict__ xb) {
  __shared__ float sx[H_DIM];
  __shared__ float slog[E_NUM];
  int t = blockIdx.x;
  const float* xr = x + (size_t)t * H_DIM;
  for (int i = threadIdx.x; i < H_DIM / 4; i += 256)
    ((float4*)sx)[i] = ((const float4*)xr)[i];
  __syncthreads();

  if (xb) {  // free bf16 conversion of x while the row is in LDS
    for (int i = threadIdx.x; i < H_DIM / 8; i += 256) {
      const float* s = sx + i * 8;
      bf16x8 b;
#pragma unroll
      for (int j = 0; j < 8; j++) b[j] = (bf16_t)s[j];
      *(bf16x8*)&xb[(size_t)t * H_DIM + i * 8] = b;
    }
  }

  int e = threadIdx.x >> 3;  // 32 experts x 8 threads
  int p = threadIdx.x & 7;
  const float* gw = gate_w + (size_t)e * H_DIM;
  float acc = 0.f;
  for (int h = p; h < H_DIM; h += 8) acc += sx[h] * gw[h];
  acc += __shfl_xor(acc, 1);
  acc += __shfl_xor(acc, 2);
  acc += __shfl_xor(acc, 4);
  if (p == 0) slog[e] = acc;
  __syncthreads();

  if (threadIdx.x == 0) {
    float v[E_NUM];
    for (int i = 0; i < E_NUM; i++) v[i] = slog[i];
    int idx[K_TOP];
    float val[K_TOP];
    for (int k = 0; k < K_TOP; k++) {
      int bi = 0;
      float bv = -1e30f;
      for (int i = 0; i < E_NUM; i++)
        if (v[i] > bv) { bv = v[i]; bi = i; }
      idx[k] = bi; val[k] = bv; v[bi] = -1e30f;
    }
    float m = val[0], s = 0.f, w[K_TOP];
    for (int k = 0; k < K_TOP; k++) { w[k] = __expf(val[k] - m); s += w[k]; }
    float inv = 1.f / s;
    for (int k = 0; k < K_TOP; k++) {
      topk_idx[t * K_TOP + k] = idx[k];
      topk_wt[t * K_TOP + k] = w[k] * inv;
      atomicAdd(&counts[idx[k]], 1);
    }
  }
}

__global__ void scan_kernel(const int* __restrict__ counts,
                            int* __restrict__ offsets) {
  if (threadIdx.x == 0 && blockIdx.x == 0) {
    int acc = 0;
    for (int e = 0; e < E_NUM; e++) { offsets[e] = acc; acc += counts[e]; }
    offsets[E_NUM] = acc;
  }
}

__global__ __launch_bounds__(256) void build_kernel(
    const int* __restrict__ topk_idx, const float* __restrict__ topk_wt,
    const int* __restrict__ offsets, int* __restrict__ cursors,
    int* __restrict__ token_list, float* __restrict__ slot_wt,
    int* __restrict__ slot_of) {
  int t = blockIdx.x * 256 + threadIdx.x;
  if (t >= T_TOK) return;
  for (int k = 0; k < K_TOP; k++) {
    int e = topk_idx[t * K_TOP + k];
    int pos = atomicAdd(&cursors[e], 1);
    int slot = offsets[e] + pos;
    token_list[slot] = t;
    slot_wt[slot] = topk_wt[t * K_TOP + k];
    slot_of[t * K_TOP + k] = slot;
  }
}

// ------- Weight conversion: [E][R][C] fp32 -> [E][C][R] bf16 (transpose) ---
__global__ __launch_bounds__(256) void conv_transpose(
    const float* __restrict__ in, bf16_t* __restrict__ out, int R, int C) {
  __shared__ bf16_t sT[64][72];  // 144B row stride: 16B-aligned vector reads
  int e = blockIdx.z;
  int r0 = blockIdx.x * 64;
  int c0 = blockIdx.y * 64;
  const float* src = in + ((size_t)e * R + r0) * C + c0;
  bf16_t* dst = out + ((size_t)e * C + c0) * R + r0;
  int tid = threadIdx.x;
#pragma unroll
  for (int it = 0; it < 4; ++it) {
    int idx = it * 256 + tid;
    int r = idx >> 4;
    int c4 = (idx & 15) * 4;
    float4 f = *(const float4*)&src[(size_t)r * C + c4];
    sT[c4 + 0][r] = (bf16_t)f.x;
    sT[c4 + 1][r] = (bf16_t)f.y;
    sT[c4 + 2][r] = (bf16_t)f.z;
    sT[c4 + 3][r] = (bf16_t)f.w;
  }
  __syncthreads();
#pragma unroll
  for (int it = 0; it < 2; ++it) {
    int idx = it * 256 + tid;
    int c = idx >> 3;
    int r8 = (idx & 7) * 8;
    bf16x8 b = *(const bf16x8*)&sT[c][r8];
    *(bf16x8*)&dst[(size_t)c * R + r8] = b;
  }
}

// ---------------- Fast GEMMs: m97-style, global_load_lds + XOR swizzle -----
// LDS tiles are row-major [rows][BK=64 bf16] = 8 chunks of 16B per row.
// global_load_lds writes LINEAR; source chunk is pre-swizzled c = c' ^ (row&7);
// ds_read uses the same XOR -> bank-conflict-free b128 fragment reads.
#define GBM 128
#define GBN 64
#define GBK 64

__global__ __launch_bounds__(256) void gateup_fast(
    const bf16_t* __restrict__ xb, const bf16_t* __restrict__ wgb,
    const bf16_t* __restrict__ wub, const int* __restrict__ counts,
    const int* __restrict__ offsets, const int* __restrict__ token_list,
    bf16_t* __restrict__ hbuf) {
  int e = blockIdx.z;
  int cnt = counts[e];
  int m_base = blockIdx.x * GBM;
  if (m_base >= cnt) return;
  int n_base = blockIdx.y * GBN;
  int off = offsets[e];

  __shared__ bf16_t sA[GBM * GBK];   // 16 KB
  __shared__ bf16_t sBg[GBN * GBK];  // 8 KB
  __shared__ bf16_t sBu[GBN * GBK];  // 8 KB
  __shared__ int sTok[GBM];

  int tid = threadIdx.x;
  if (tid < GBM) {
    int s = m_base + tid;
    sTok[tid] = (s < cnt) ? token_list[off + s] : 0;  // pad rows read token 0
  }
  __syncthreads();

  int lane = tid & 63;
  int wv = tid >> 6;
  int wm = (wv >> 1) * 64;  // 2x2 wave grid, 64x32 per wave per matrix
  int wn = (wv & 1) * 32;
  int l15 = lane & 15;
  int q = lane >> 4;

  // staging source pointers (dest is linear: flat chunk f = it*256 + tid)
  const bf16_t* asrc[4];
#pragma unroll
  for (int it = 0; it < 4; ++it) {
    int f = it * 256 + tid;
    int r = f >> 3;
    int c = (f & 7) ^ (r & 7);
    asrc[it] = xb + (size_t)sTok[r] * H_DIM + c * 8;
  }
  const bf16_t *bgs[2], *bus[2];
#pragma unroll
  for (int it = 0; it < 2; ++it) {
    int f = it * 256 + tid;
    int n = f >> 3;
    int c = (f & 7) ^ (n & 7);
    size_t o = ((size_t)e * I_DIM + n_base + n) * H_DIM + c * 8;
    bgs[it] = wgb + o;
    bus[it] = wub + o;
  }

  floatx4 zero = {0.f, 0.f, 0.f, 0.f};
  floatx4 ag[4][2], au[4][2];
#pragma unroll
  for (int mi = 0; mi < 4; ++mi)
#pragma unroll
    for (int ni = 0; ni < 2; ++ni) { ag[mi][ni] = zero; au[mi][ni] = zero; }

  char* sAb = (char*)sA;
  char* sBgb = (char*)sBg;
  char* sBub = (char*)sBu;

  for (int k0 = 0; k0 < H_DIM; k0 += GBK) {
#pragma unroll
    for (int it = 0; it < 4; ++it)
      async_lds16(asrc[it] + k0, sAb + (it * 256 + wv * 64) * 16);
#pragma unroll
    for (int it = 0; it < 2; ++it) {
      async_lds16(bgs[it] + k0, sBgb + (it * 256 + wv * 64) * 16);
      async_lds16(bus[it] + k0, sBub + (it * 256 + wv * 64) * 16);
    }
    __syncthreads();

#pragma unroll
    for (int ks = 0; ks < 2; ++ks) {
      bf16x8 af[4], bg[2], bu[2];
#pragma unroll
      for (int mi = 0; mi < 4; ++mi) {
        int r = wm + mi * 16 + l15;
        int c = (ks * 4 + q) ^ (r & 7);
        af[mi] = *(const bf16x8*)&sA[(r * 8 + c) * 8];
      }
#pragma unroll
      for (int ni = 0; ni < 2; ++ni) {
        int r = wn + ni * 16 + l15;
        int c = (ks * 4 + q) ^ (r & 7);
        bg[ni] = *(const bf16x8*)&sBg[(r * 8 + c) * 8];
        bu[ni] = *(const bf16x8*)&sBu[(r * 8 + c) * 8];
      }
#pragma unroll
      for (int mi = 0; mi < 4; ++mi)
#pragma unroll
        for (int ni = 0; ni < 2; ++ni) {
          ag[mi][ni] = __builtin_amdgcn_mfma_f32_16x16x32_bf16(
              af[mi], bg[ni], ag[mi][ni], 0, 0, 0);
          au[mi][ni] = __builtin_amdgcn_mfma_f32_16x16x32_bf16(
              af[mi], bu[ni], au[mi][ni], 0, 0, 0);
        }
    }
    __syncthreads();
  }

  // epilogue: h = silu(g)*u. C layout: col=lane&15, row=q*4+reg.
#pragma unroll
  for (int mi = 0; mi < 4; ++mi)
#pragma unroll
    for (int ni = 0; ni < 2; ++ni)
#pragma unroll
      for (int r = 0; r < 4; ++r) {
        int row = wm + mi * 16 + q * 4 + r;
        if (m_base + row < cnt) {
          int col = n_base + wn + ni * 16 + l15;
          float g = ag[mi][ni][r];
          float u = au[mi][ni][r];
          float hv = g * (1.f / (1.f + __expf(-g))) * u;
          hbuf[(size_t)(off + m_base + row) * I_DIM + col] = (bf16_t)hv;
        }
      }
}

#define DBM 128
#define DBN 128
#define DBK 64

__global__ __launch_bounds__(256) void down_fast(
    const bf16_t* __restrict__ hbuf, const bf16_t* __restrict__ wdb,
    const int* __restrict__ counts, const int* __restrict__ offsets,
    const float* __restrict__ slot_wt, bf16_t* __restrict__ ybuf) {
  int e = blockIdx.z;
  int cnt = counts[e];
  int m_base = blockIdx.x * DBM;
  if (m_base >= cnt) return;
  int n_base = blockIdx.y * DBN;
  int off = offsets[e];

  __shared__ bf16_t sA[DBM * DBK];  // 16 KB
  __shared__ bf16_t sB[DBN * DBK];  // 16 KB
  __shared__ float sW[DBM];

  int tid = threadIdx.x;
  if (tid < DBM) {
    int s = m_base + tid;
    sW[tid] = (s < cnt) ? slot_wt[off + s] : 0.f;
  }

  int lane = tid & 63;
  int wv = tid >> 6;
  int wm = (wv >> 1) * 64;  // 2x2 wave grid, 64x64 per wave
  int wn = (wv & 1) * 64;
  int l15 = lane & 15;
  int q = lane >> 4;

  const bf16_t* asrc[4];
  const bf16_t* bsrc[4];
#pragma unroll
  for (int it = 0; it < 4; ++it) {
    int f = it * 256 + tid;
    int r = f >> 3;
    int c = (f & 7) ^ (r & 7);
    asrc[it] = hbuf + (size_t)(off + m_base + r) * I_DIM + c * 8;
    bsrc[it] = wdb + ((size_t)e * H_DIM + n_base + r) * I_DIM + c * 8;
  }

  floatx4 zero = {0.f, 0.f, 0.f, 0.f};
  floatx4 acc[4][4];
#pragma unroll
  for (int mi = 0; mi < 4; ++mi)
#pragma unroll
    for (int ni = 0; ni < 4; ++ni) acc[mi][ni] = zero;

  char* sAb = (char*)sA;
  char* sBb = (char*)sB;

  for (int k0 = 0; k0 < I_DIM; k0 += DBK) {
#pragma unroll
    for (int it = 0; it < 4; ++it) {
      async_lds16(asrc[it] + k0, sAb + (it * 256 + wv * 64) * 16);
      async_lds16(bsrc[it] + k0, sBb + (it * 256 + wv * 64) * 16);
    }
    __syncthreads();

#pragma unroll
    for (int ks = 0; ks < 2; ++ks) {
      bf16x8 af[4], bf_[4];
#pragma unroll
      for (int mi = 0; mi < 4; ++mi) {
        int r = wm + mi * 16 + l15;
        int c = (ks * 4 + q) ^ (r & 7);
        af[mi] = *(const bf16x8*)&sA[(r * 8 + c) * 8];
      }
#pragma unroll
      for (int ni = 0; ni < 4; ++ni) {
        int r = wn + ni * 16 + l15;
        int c = (ks * 4 + q) ^ (r & 7);
        bf_[ni] = *(const bf16x8*)&sB[(r * 8 + c) * 8];
      }
#pragma unroll
      for (int mi = 0; mi < 4; ++mi)
#pragma unroll
        for (int ni = 0; ni < 4; ++ni)
          acc[mi][ni] = __builtin_amdgcn_mfma_f32_16x16x32_bf16(
              af[mi], bf_[ni], acc[mi][ni], 0, 0, 0);
    }
    __syncthreads();
  }

#pragma unroll
  for (int mi = 0; mi < 4; ++mi)
#pragma unroll
    for (int ni = 0; ni < 4; ++ni)
#pragma unroll
      for (int r = 0; r < 4; ++r) {
        int row = wm + mi * 16 + q * 4 + r;
        if (m_base + row < cnt) {
          int col = n_base + wn + ni * 16 + l15;
          float v = acc[mi][ni][r] * sW[row];
          ybuf[(size_t)(off + m_base + row) * H_DIM + col] = (bf16_t)v;
        }
      }
}

// ---------------- Legacy fallback GEMMs (ws too small) ---------------------
#define BM 64
#define BN 64
#define BK 32
#define LDK 40

__global__ __launch_bounds__(256) void gateup_kernel(
    const float* __restrict__ x, const float* __restrict__ w_gate,
    const float* __restrict__ w_up, const int* __restrict__ counts,
    const int* __restrict__ offsets, const int* __restrict__ token_list,
    bf16_t* __restrict__ hbuf) {
  int e = blockIdx.z;
  int cnt = counts[e];
  int m_base = blockIdx.x * BM;
  if (m_base >= cnt) return;
  int n_base = blockIdx.y * BN;
  int off = offsets[e];

  __shared__ bf16_t sA[BM][LDK];
  __shared__ bf16_t sBg[BN][LDK];
  __shared__ bf16_t sBu[BN][LDK];
  __shared__ int sTok[BM];

  int tid = threadIdx.x;
  if (tid < BM) {
    int s = m_base + tid;
    sTok[tid] = (s < cnt) ? token_list[off + s] : -1;
  }
  __syncthreads();

  int lane = tid & 63;
  int wv = tid >> 6;
  int wm = (wv >> 1) * 32;
  int wn = (wv & 1) * 32;
  int l15 = lane & 15;
  int q = lane >> 4;

  floatx4 zero = {0.f, 0.f, 0.f, 0.f};
  floatx4 ag[2][2], au[2][2];
  for (int i = 0; i < 2; i++)
    for (int j = 0; j < 2; j++) { ag[i][j] = zero; au[i][j] = zero; }

  int ar = tid >> 2;
  int ac = (tid & 3) * 8;
  int bn = tid & 63;
  int bk = (tid >> 6) * 8;

  const float* wg_base = w_gate + (size_t)e * H_DIM * I_DIM + n_base + bn;
  const float* wu_base = w_up + (size_t)e * H_DIM * I_DIM + n_base + bn;

  for (int k0 = 0; k0 < H_DIM; k0 += BK) {
    {
      int tok = sTok[ar];
      float v[8];
      if (tok >= 0) {
        const float* src = x + (size_t)tok * H_DIM + k0 + ac;
        float4 f0 = ((const float4*)src)[0];
        float4 f1 = ((const float4*)src)[1];
        v[0] = f0.x; v[1] = f0.y; v[2] = f0.z; v[3] = f0.w;
        v[4] = f1.x; v[5] = f1.y; v[6] = f1.z; v[7] = f1.w;
      } else {
        for (int j = 0; j < 8; j++) v[j] = 0.f;
      }
      bf16x8 b;
      for (int j = 0; j < 8; j++) b[j] = (bf16_t)v[j];
      *(bf16x8*)&sA[ar][ac] = b;
    }
    {
      bf16x8 bg, bu;
      const float* pg = wg_base + (size_t)(k0 + bk) * I_DIM;
      const float* pu = wu_base + (size_t)(k0 + bk) * I_DIM;
#pragma unroll
      for (int j = 0; j < 8; j++) {
        bg[j] = (bf16_t)pg[(size_t)j * I_DIM];
        bu[j] = (bf16_t)pu[(size_t)j * I_DIM];
      }
      *(bf16x8*)&sBg[bn][bk] = bg;
      *(bf16x8*)&sBu[bn][bk] = bu;
    }
    __syncthreads();

    bf16x8 af[2], bgf[2], buf_[2];
#pragma unroll
    for (int mi = 0; mi < 2; mi++)
      af[mi] = *(bf16x8*)&sA[wm + mi * 16 + l15][q * 8];
#pragma unroll
    for (int ni = 0; ni < 2; ni++) {
      bgf[ni] = *(bf16x8*)&sBg[wn + ni * 16 + l15][q * 8];
      buf_[ni] = *(bf16x8*)&sBu[wn + ni * 16 + l15][q * 8];
    }
#pragma unroll
    for (int mi = 0; mi < 2; mi++)
#pragma unroll
      for (int ni = 0; ni < 2; ni++) {
        ag[mi][ni] = __builtin_amdgcn_mfma_f32_16x16x32_bf16(
            af[mi], bgf[ni], ag[mi][ni], 0, 0, 0);
        au[mi][ni] = __builtin_amdgcn_mfma_f32_16x16x32_bf16(
            af[mi], buf_[ni], au[mi][ni], 0, 0, 0);
      }
    __syncthreads();
  }

#pragma unroll
  for (int mi = 0; mi < 2; mi++)
#pragma unroll
    for (int ni = 0; ni < 2; ni++)
#pragma unroll
      for (int r = 0; r < 4; r++) {
        int row = wm + mi * 16 + q * 4 + r;
        int col = wn + ni * 16 + l15;
        if (m_base + row < cnt) {
          float g = ag[mi][ni][r];
          float u = au[mi][ni][r];
          float hv = g * (1.f / (1.f + __expf(-g))) * u;
          hbuf[(size_t)(off + m_base + row) * I_DIM + n_base + col] =
              (bf16_t)hv;
        }
      }
}

template <bool ATOMIC>
__global__ __launch_bounds__(256) void down_kernel(
    const bf16_t* __restrict__ hbuf, const float* __restrict__ w_down,
    const int* __restrict__ counts, const int* __restrict__ offsets,
    const float* __restrict__ slot_wt, const int* __restrict__ token_list,
    bf16_t* __restrict__ ybuf, float* __restrict__ out) {
  int e = blockIdx.z;
  int cnt = counts[e];
  int m_base = blockIdx.x * BM;
  if (m_base >= cnt) return;
  int n_base = blockIdx.y * BN;
  int off = offsets[e];

  __shared__ bf16_t sA[BM][LDK];
  __shared__ bf16_t sB[BN][LDK];
  __shared__ float sW[BM];
  __shared__ int sTok[BM];

  int tid = threadIdx.x;
  if (tid < BM) {
    int s = m_base + tid;
    bool v = (s < cnt);
    sW[tid] = v ? slot_wt[off + s] : 0.f;
    sTok[tid] = v ? token_list[off + s] : 0;
  }
  __syncthreads();

  int lane = tid & 63;
  int wv = tid >> 6;
  int wm = (wv >> 1) * 32;
  int wn = (wv & 1) * 32;
  int l15 = lane & 15;
  int q = lane >> 4;

  floatx4 zero = {0.f, 0.f, 0.f, 0.f};
  floatx4 acc[2][2];
  for (int i = 0; i < 2; i++)
    for (int j = 0; j < 2; j++) acc[i][j] = zero;

  int ar = tid >> 2;
  int ac = (tid & 3) * 8;
  int bn = tid & 63;
  int bk = (tid >> 6) * 8;

  const float* wd_base = w_down + (size_t)e * I_DIM * H_DIM + n_base + bn;

  for (int k0 = 0; k0 < I_DIM; k0 += BK) {
    {
      bf16x8 a;
      if (m_base + ar < cnt) {
        a = *(const bf16x8*)&hbuf[(size_t)(off + m_base + ar) * I_DIM + k0 + ac];
      } else {
        for (int j = 0; j < 8; j++) a[j] = (bf16_t)0.f;
      }
      *(bf16x8*)&sA[ar][ac] = a;
    }
    {
      bf16x8 b;
      const float* pd = wd_base + (size_t)(k0 + bk) * H_DIM;
#pragma unroll
      for (int j = 0; j < 8; j++) b[j] = (bf16_t)pd[(size_t)j * H_DIM];
      *(bf16x8*)&sB[bn][bk] = b;
    }
    __syncthreads();

    bf16x8 af[2], bf[2];
#pragma unroll
    for (int mi = 0; mi < 2; mi++)
      af[mi] = *(bf16x8*)&sA[wm + mi * 16 + l15][q * 8];
#pragma unroll
    for (int ni = 0; ni < 2; ni++)
      bf[ni] = *(bf16x8*)&sB[wn + ni * 16 + l15][q * 8];
#pragma unroll
    for (int mi = 0; mi < 2; mi++)
#pragma unroll
      for (int ni = 0; ni < 2; ni++)
        acc[mi][ni] = __builtin_amdgcn_mfma_f32_16x16x32_bf16(
            af[mi], bf[ni], acc[mi][ni], 0, 0, 0);
    __syncthreads();
  }

#pragma unroll
  for (int mi = 0; mi < 2; mi++)
#pragma unroll
    for (int ni = 0; ni < 2; ni++)
#pragma unroll
      for (int r = 0; r < 4; r++) {
        int row = wm + mi * 16 + q * 4 + r;
        int col = wn + ni * 16 + l15;
        if (m_base + row < cnt) {
          float v = acc[mi][ni][r] * sW[row];
          if (ATOMIC) {
            atomicAdd(&out[(size_t)sTok[row] * H_DIM + n_base + col], v);
          } else {
            ybuf[(size_t)(off + m_base + row) * H_DIM + n_base + col] =
                (bf16_t)v;
          }
        }
      }
}

__global__ __launch_bounds__(256) void gather_kernel(
    const bf16_t* __restrict__ ybuf, const int* __restrict__ slot_of,
    float* __restrict__ out) {
  int g = blockIdx.x * 256 + threadIdx.x;
  int t = g >> 7;
  int c = (g & 127) * 8;
  float acc[8];
#pragma unroll
  for (int j = 0; j < 8; j++) acc[j] = 0.f;
#pragma unroll
  for (int k = 0; k < K_TOP; k++) {
    int slot = slot_of[t * K_TOP + k];
    bf16x8 yv = *(const bf16x8*)&ybuf[(size_t)slot * H_DIM + c];
#pragma unroll
    for (int j = 0; j < 8; j++) acc[j] += (float)yv[j];
  }
  float4* o = (float4*)(out + (size_t)t * H_DIM + c);
  o[0] = make_float4(acc[0], acc[1], acc[2], acc[3]);
  o[1] = make_float4(acc[4], acc[5], acc[6], acc[7]);
}

extern "C" void kernel_launch(void* const* d_in, const int* in_sizes, int n_in,
                              void* d_out, int out_size, void* d_ws,
                              size_t ws_size, hipStream_t stream) {
  const float* x = (const float*)d_in[0];
  const float* gate_w = (const float*)d_in[1];
  const float* w_gate = (const float*)d_in[2];
  const float* w_up = (const float*)d_in[3];
  const float* w_down = (const float*)d_in[4];
  float* out = (float*)d_out;

  char* ws = (char*)d_ws;
  int* counts = (int*)(ws + 0);
  int* cursors = (int*)(ws + 128);
  int* offsets = (int*)(ws + 256);
  int* topk_idx = (int*)(ws + 512);
  float* topk_wt = (float*)(ws + 512 + 131072);
  int* slot_of = (int*)(ws + 512 + 2 * 131072);
  int* token_list = (int*)(ws + 512 + 3 * 131072);
  float* slot_wt = (float*)(ws + 512 + 4 * 131072);

  const size_t H_BASE = 1ull << 20;
  const size_t H_BYTES = (size_t)NSLOT * I_DIM * 2;       // 32 MB
  const size_t Y_BYTES = (size_t)NSLOT * H_DIM * 2;       // 64 MB
  const size_t X_BYTES = (size_t)T_TOK * H_DIM * 2;       // 16 MB
  const size_t W_BYTES = (size_t)E_NUM * H_DIM * I_DIM * 2;  // 32 MB each
  bf16_t* hbuf = (bf16_t*)(ws + H_BASE);
  bf16_t* ybuf = (bf16_t*)(ws + H_BASE + H_BYTES);
  bf16_t* xb = (bf16_t*)(ws + H_BASE + H_BYTES + Y_BYTES);
  bf16_t* wgb = (bf16_t*)(ws + H_BASE + H_BYTES + Y_BYTES + X_BYTES);
  bf16_t* wub = (bf16_t*)(ws + H_BASE + H_BYTES + Y_BYTES + X_BYTES + W_BYTES);
  bf16_t* wdb =
      (bf16_t*)(ws + H_BASE + H_BYTES + Y_BYTES + X_BYTES + 2 * W_BYTES);

  bool fast = ws_size >= H_BASE + H_BYTES + Y_BYTES + X_BYTES + 3 * W_BYTES;
  bool gather_path = ws_size >= H_BASE + H_BYTES + Y_BYTES;

  hipMemsetAsync(ws, 0, 512, stream);

  if (fast) {
    router_kernel<<<T_TOK, 256, 0, stream>>>(x, gate_w, counts, topk_idx,
                                             topk_wt, xb);
    conv_transpose<<<dim3(H_DIM / 64, I_DIM / 64, E_NUM), 256, 0, stream>>>(
        w_gate, wgb, H_DIM, I_DIM);
    conv_transpose<<<dim3(H_DIM / 64, I_DIM / 64, E_NUM), 256, 0, stream>>>(
        w_up, wub, H_DIM, I_DIM);
    conv_transpose<<<dim3(I_DIM / 64, H_DIM / 64, E_NUM), 256, 0, stream>>>(
        w_down, wdb, I_DIM, H_DIM);
    scan_kernel<<<1, 64, 0, stream>>>(counts, offsets);
    build_kernel<<<T_TOK / 256, 256, 0, stream>>>(
        topk_idx, topk_wt, offsets, cursors, token_list, slot_wt, slot_of);
    gateup_fast<<<dim3(T_TOK / GBM, I_DIM / GBN, E_NUM), 256, 0, stream>>>(
        xb, wgb, wub, counts, offsets, token_list, hbuf);
    down_fast<<<dim3(T_TOK / DBM, H_DIM / DBN, E_NUM), 256, 0, stream>>>(
        hbuf, wdb, counts, offsets, slot_wt, ybuf);
    gather_kernel<<<(T_TOK * (H_DIM / 8)) / 256, 256, 0, stream>>>(
        ybuf, slot_of, out);
  } else {
    router_kernel<<<T_TOK, 256, 0, stream>>>(x, gate_w, counts, topk_idx,
                                             topk_wt, nullptr);
    scan_kernel<<<1, 64, 0, stream>>>(counts, offsets);
    build_kernel<<<T_TOK / 256, 256, 0, stream>>>(
        topk_idx, topk_wt, offsets, cursors, token_list, slot_wt, slot_of);
    gateup_kernel<<<dim3(T_TOK / BM, I_DIM / BN, E_NUM), 256, 0, stream>>>(
        x, w_gate, w_up, counts, offsets, token_list, hbuf);
    if (gather_path) {
      down_kernel<false>
          <<<dim3(T_TOK / BM, H_DIM / BN, E_NUM), 256, 0, stream>>>(
              hbuf, w_down, counts, offsets, slot_wt, token_list, ybuf, out);
      gather_kernel<<<(T_TOK * (H_DIM / 8)) / 256, 256, 0, stream>>>(
          ybuf, slot_of, out);
    } else {
      hipMemsetAsync(out, 0, (size_t)out_size * sizeof(float), stream);
      down_kernel<true>
          <<<dim3(T_TOK / BM, H_DIM / BN, E_NUM), 256, 0, stream>>>(
              hbuf, w_down, counts, offsets, slot_wt, token_list, ybuf, out);
    }
  }
}

// Round 2
// 778.874 us; speedup vs baseline: 1.3474x; 1.3474x over previous
//
#include <hip/hip_runtime.h>
#include <hip/hip_bf16.h>

// Qwen3 MoE block: T=8192 tokens, H=1024, I=512, E=32, top-4.
// Fast path: router(+x->bf16) -> w->bf16 transpose -> scan(+tile map) ->
//   gateup GEMM (2-phase dbuf, global_load_lds, swizzled) -> down GEMM ->
//   gather.

#define T_TOK 8192
#define H_DIM 1024
#define I_DIM 512
#define E_NUM 32
#define K_TOP 4
#define NSLOT (T_TOK * K_TOP)
#define MAX_TILES 288  // NSLOT/128 + E_NUM

typedef __bf16 bf16_t;
typedef __bf16 bf16x8 __attribute__((ext_vector_type(8)));
typedef float floatx4 __attribute__((ext_vector_type(4)));

__device__ __forceinline__ void async_lds16(const void* g, void* l) {
  __builtin_amdgcn_global_load_lds(
      (const __attribute__((address_space(1))) void*)g,
      (__attribute__((address_space(3))) void*)l, 16, 0, 0);
}

// ---------------- Router: one block per token (also emits bf16 x) ----------
__global__ __launch_bounds__(256) void router_kernel(
    const float* __restrict__ x, const float* __restrict__ gate_w,
    int* __restrict__ counts, int* __restrict__ topk_idx,
    float* __restrict__ topk_wt, bf16_t* __restrict__ xb) {
  __shared__ float sx[H_DIM];
  __shared__ float slog[E_NUM];
  int t = blockIdx.x;
  const float* xr = x + (size_t)t * H_DIM;
  for (int i = threadIdx.x; i < H_DIM / 4; i += 256)
    ((float4*)sx)[i] = ((const float4*)xr)[i];
  __syncthreads();

  if (xb) {  // free bf16 conversion of x while the row is in LDS
    for (int i = threadIdx.x; i < H_DIM / 8; i += 256) {
      const float* s = sx + i * 8;
      bf16x8 b;
#pragma unroll
      for (int j = 0; j < 8; j++) b[j] = (bf16_t)s[j];
      *(bf16x8*)&xb[(size_t)t * H_DIM + i * 8] = b;
    }
  }

  int e = threadIdx.x >> 3;  // 32 experts x 8 threads
  int p = threadIdx.x & 7;
  const float* gw = gate_w + (size_t)e * H_DIM;
  float acc = 0.f;
  for (int h = p; h < H_DIM; h += 8) acc += sx[h] * gw[h];
  acc += __shfl_xor(acc, 1);
  acc += __shfl_xor(acc, 2);
  acc += __shfl_xor(acc, 4);
  if (p == 0) slog[e] = acc;
  __syncthreads();

  if (threadIdx.x == 0) {
    float v[E_NUM];
    for (int i = 0; i < E_NUM; i++) v[i] = slog[i];
    int idx[K_TOP];
    float val[K_TOP];
    for (int k = 0; k < K_TOP; k++) {
      int bi = 0;
      float bv = -1e30f;
      for (int i = 0; i < E_NUM; i++)
        if (v[i] > bv) { bv = v[i]; bi = i; }
      idx[k] = bi; val[k] = bv; v[bi] = -1e30f;
    }
    float m = val[0], s = 0.f, w[K_TOP];
    for (int k = 0; k < K_TOP; k++) { w[k] = __expf(val[k] - m); s += w[k]; }
    float inv = 1.f / s;
    for (int k = 0; k < K_TOP; k++) {
      topk_idx[t * K_TOP + k] = idx[k];
      topk_wt[t * K_TOP + k] = w[k] * inv;
      atomicAdd(&counts[idx[k]], 1);
    }
  }
}

// scan + tile map: tiles of 128 rows over each expert's slot range
__global__ void scan_kernel(const int* __restrict__ counts,
                            int* __restrict__ offsets,
                            int* __restrict__ tile_e,
                            int* __restrict__ tile_m,
                            int* __restrict__ n_tiles) {
  if (threadIdx.x == 0 && blockIdx.x == 0) {
    int acc = 0, nt = 0;
    for (int e = 0; e < E_NUM; e++) {
      offsets[e] = acc;
      int c = counts[e];
      for (int m = 0; m < c; m += 128) {
        tile_e[nt] = e;
        tile_m[nt] = m;
        nt++;
      }
      acc += c;
    }
    offsets[E_NUM] = acc;
    *n_tiles = nt;
  }
}

__global__ __launch_bounds__(256) void build_kernel(
    const int* __restrict__ topk_idx, const float* __restrict__ topk_wt,
    const int* __restrict__ offsets, int* __restrict__ cursors,
    int* __restrict__ token_list, float* __restrict__ slot_wt,
    int* __restrict__ slot_of) {
  int t = blockIdx.x * 256 + threadIdx.x;
  if (t >= T_TOK) return;
  for (int k = 0; k < K_TOP; k++) {
    int e = topk_idx[t * K_TOP + k];
    int pos = atomicAdd(&cursors[e], 1);
    int slot = offsets[e] + pos;
    token_list[slot] = t;
    slot_wt[slot] = topk_wt[t * K_TOP + k];
    slot_of[t * K_TOP + k] = slot;
  }
}

// ------- Weight conversion: [E][R][C] fp32 -> [E][C][R] bf16 (transpose) ---
__global__ __launch_bounds__(256) void conv_transpose(
    const float* __restrict__ in, bf16_t* __restrict__ out, int R, int C) {
  __shared__ bf16_t sT[64][72];
  int e = blockIdx.z;
  int r0 = blockIdx.x * 64;
  int c0 = blockIdx.y * 64;
  const float* src = in + ((size_t)e * R + r0) * C + c0;
  bf16_t* dst = out + ((size_t)e * C + c0) * R + r0;
  int tid = threadIdx.x;
#pragma unroll
  for (int it = 0; it < 4; ++it) {
    int idx = it * 256 + tid;
    int r = idx >> 4;
    int c4 = (idx & 15) * 4;
    float4 f = *(const float4*)&src[(size_t)r * C + c4];
    sT[c4 + 0][r] = (bf16_t)f.x;
    sT[c4 + 1][r] = (bf16_t)f.y;
    sT[c4 + 2][r] = (bf16_t)f.z;
    sT[c4 + 3][r] = (bf16_t)f.w;
  }
  __syncthreads();
#pragma unroll
  for (int it = 0; it < 2; ++it) {
    int idx = it * 256 + tid;
    int c = idx >> 3;
    int r8 = (idx & 7) * 8;
    bf16x8 b = *(const bf16x8*)&sT[c][r8];
    *(bf16x8*)&dst[(size_t)c * R + r8] = b;
  }
}

// ---------------- Fast GEMMs: 2-phase double-buffered pipeline -------------
// LDS tiles row-major [rows][BK=64 bf16] = 8 x 16B chunks per row.
// global_load_lds writes LINEAR; source chunk pre-swizzled c = c' ^ (row&7);
// ds_read applies the same XOR -> conflict-free b128 fragment reads.
// Pipeline: STAGE(buf^1, t+1) issued BEFORE compute(buf) -> the barrier's
// vmcnt(0) drain has the whole MFMA phase in flight behind it.
#define GBM 128
#define GBN 64
#define GBK 64
#define G_NSTEP (H_DIM / GBK)

__global__ __launch_bounds__(256) void gateup_fast(
    const bf16_t* __restrict__ xb, const bf16_t* __restrict__ wgb,
    const bf16_t* __restrict__ wub, const int* __restrict__ counts,
    const int* __restrict__ offsets, const int* __restrict__ token_list,
    const int* __restrict__ tile_e, const int* __restrict__ tile_m,
    const int* __restrict__ n_tiles, bf16_t* __restrict__ hbuf) {
  int xt = blockIdx.x;
  if (xt >= *n_tiles) return;
  int e = tile_e[xt];
  int m_base = tile_m[xt];
  int cnt = counts[e];
  int off = offsets[e];
  int n_base = blockIdx.y * GBN;

  __shared__ bf16_t sA[2][GBM * GBK];   // 2 x 16 KB
  __shared__ bf16_t sBg[2][GBN * GBK];  // 2 x 8 KB
  __shared__ bf16_t sBu[2][GBN * GBK];  // 2 x 8 KB
  __shared__ int sTok[GBM];

  int tid = threadIdx.x;
  if (tid < GBM) {
    int s = m_base + tid;
    sTok[tid] = (s < cnt) ? token_list[off + s] : 0;
  }
  __syncthreads();

  int lane = tid & 63;
  int wv = tid >> 6;
  int wm = (wv >> 1) * 64;
  int wn = (wv & 1) * 32;
  int l15 = lane & 15;
  int q = lane >> 4;

  const bf16_t* asrc[4];
#pragma unroll
  for (int it = 0; it < 4; ++it) {
    int f = it * 256 + tid;
    int r = f >> 3;
    int c = (f & 7) ^ (r & 7);
    asrc[it] = xb + (size_t)sTok[r] * H_DIM + c * 8;
  }
  const bf16_t *bgs[2], *bus[2];
#pragma unroll
  for (int it = 0; it < 2; ++it) {
    int f = it * 256 + tid;
    int n = f >> 3;
    int c = (f & 7) ^ (n & 7);
    size_t o = ((size_t)e * I_DIM + n_base + n) * H_DIM + c * 8;
    bgs[it] = wgb + o;
    bus[it] = wub + o;
  }

  floatx4 zero = {0.f, 0.f, 0.f, 0.f};
  floatx4 ag[4][2], au[4][2];
#pragma unroll
  for (int mi = 0; mi < 4; ++mi)
#pragma unroll
    for (int ni = 0; ni < 2; ++ni) { ag[mi][ni] = zero; au[mi][ni] = zero; }

  auto stage = [&](int buf, int k0) {
    char* a = (char*)sA[buf];
    char* g = (char*)sBg[buf];
    char* u = (char*)sBu[buf];
#pragma unroll
    for (int it = 0; it < 4; ++it)
      async_lds16(asrc[it] + k0, a + (it * 256 + wv * 64) * 16);
#pragma unroll
    for (int it = 0; it < 2; ++it) {
      async_lds16(bgs[it] + k0, g + (it * 256 + wv * 64) * 16);
      async_lds16(bus[it] + k0, u + (it * 256 + wv * 64) * 16);
    }
  };

  // prologue: tile 0 into buf 0
  stage(0, 0);
  __syncthreads();

  int cur = 0;
  for (int t = 0; t < G_NSTEP; ++t) {
    if (t + 1 < G_NSTEP) stage(cur ^ 1, (t + 1) * GBK);  // prefetch next

#pragma unroll
    for (int ks = 0; ks < 2; ++ks) {
      bf16x8 af[4], bg[2], bu[2];
#pragma unroll
      for (int mi = 0; mi < 4; ++mi) {
        int r = wm + mi * 16 + l15;
        int c = (ks * 4 + q) ^ (r & 7);
        af[mi] = *(const bf16x8*)&sA[cur][(r * 8 + c) * 8];
      }
#pragma unroll
      for (int ni = 0; ni < 2; ++ni) {
        int r = wn + ni * 16 + l15;
        int c = (ks * 4 + q) ^ (r & 7);
        bg[ni] = *(const bf16x8*)&sBg[cur][(r * 8 + c) * 8];
        bu[ni] = *(const bf16x8*)&sBu[cur][(r * 8 + c) * 8];
      }
#pragma unroll
      for (int mi = 0; mi < 4; ++mi)
#pragma unroll
        for (int ni = 0; ni < 2; ++ni) {
          ag[mi][ni] = __builtin_amdgcn_mfma_f32_16x16x32_bf16(
              af[mi], bg[ni], ag[mi][ni], 0, 0, 0);
          au[mi][ni] = __builtin_amdgcn_mfma_f32_16x16x32_bf16(
              af[mi], bu[ni], au[mi][ni], 0, 0, 0);
        }
    }
    __syncthreads();  // drains vmcnt(0): prefetched loads had compute in flight
    cur ^= 1;
  }

  // epilogue: h = silu(g)*u. C layout: col=lane&15, row=q*4+reg.
#pragma unroll
  for (int mi = 0; mi < 4; ++mi)
#pragma unroll
    for (int ni = 0; ni < 2; ++ni)
#pragma unroll
      for (int r = 0; r < 4; ++r) {
        int row = wm + mi * 16 + q * 4 + r;
        if (m_base + row < cnt) {
          int col = n_base + wn + ni * 16 + l15;
          float g = ag[mi][ni][r];
          float u = au[mi][ni][r];
          float hv = g * (1.f / (1.f + __expf(-g))) * u;
          hbuf[(size_t)(off + m_base + row) * I_DIM + col] = (bf16_t)hv;
        }
      }
}

#define DBM 128
#define DBN 128
#define DBK 64
#define D_NSTEP (I_DIM / DBK)

__global__ __launch_bounds__(256) void down_fast(
    const bf16_t* __restrict__ hbuf, const bf16_t* __restrict__ wdb,
    const int* __restrict__ counts, const int* __restrict__ offsets,
    const float* __restrict__ slot_wt, const int* __restrict__ tile_e,
    const int* __restrict__ tile_m, const int* __restrict__ n_tiles,
    bf16_t* __restrict__ ybuf) {
  int xt = blockIdx.x;
  if (xt >= *n_tiles) return;
  int e = tile_e[xt];
  int m_base = tile_m[xt];
  int cnt = counts[e];
  int off = offsets[e];
  int n_base = blockIdx.y * DBN;

  __shared__ bf16_t sA[2][DBM * DBK];  // 2 x 16 KB
  __shared__ bf16_t sB[2][DBN * DBK];  // 2 x 16 KB
  __shared__ float sW[DBM];

  int tid = threadIdx.x;
  if (tid < DBM) {
    int s = m_base + tid;
    sW[tid] = (s < cnt) ? slot_wt[off + s] : 0.f;
  }

  int lane = tid & 63;
  int wv = tid >> 6;
  int wm = (wv >> 1) * 64;
  int wn = (wv & 1) * 64;
  int l15 = lane & 15;
  int q = lane >> 4;

  const bf16_t* asrc[4];
  const bf16_t* bsrc[4];
#pragma unroll
  for (int it = 0; it < 4; ++it) {
    int f = it * 256 + tid;
    int r = f >> 3;
    int c = (f & 7) ^ (r & 7);
    asrc[it] = hbuf + (size_t)(off + m_base + r) * I_DIM + c * 8;
    bsrc[it] = wdb + ((size_t)e * H_DIM + n_base + r) * I_DIM + c * 8;
  }

  floatx4 zero = {0.f, 0.f, 0.f, 0.f};
  floatx4 acc[4][4];
#pragma unroll
  for (int mi = 0; mi < 4; ++mi)
#pragma unroll
    for (int ni = 0; ni < 4; ++ni) acc[mi][ni] = zero;

  auto stage = [&](int buf, int k0) {
    char* a = (char*)sA[buf];
    char* b = (char*)sB[buf];
#pragma unroll
    for (int it = 0; it < 4; ++it) {
      async_lds16(asrc[it] + k0, a + (it * 256 + wv * 64) * 16);
      async_lds16(bsrc[it] + k0, b + (it * 256 + wv * 64) * 16);
    }
  };

  stage(0, 0);
  __syncthreads();

  int cur = 0;
  for (int t = 0; t < D_NSTEP; ++t) {
    if (t + 1 < D_NSTEP) stage(cur ^ 1, (t + 1) * DBK);

#pragma unroll
    for (int ks = 0; ks < 2; ++ks) {
      bf16x8 af[4], bf_[4];
#pragma unroll
      for (int mi = 0; mi < 4; ++mi) {
        int r = wm + mi * 16 + l15;
        int c = (ks * 4 + q) ^ (r & 7);
        af[mi] = *(const bf16x8*)&sA[cur][(r * 8 + c) * 8];
      }
#pragma unroll
      for (int ni = 0; ni < 4; ++ni) {
        int r = wn + ni * 16 + l15;
        int c = (ks * 4 + q) ^ (r & 7);
        bf_[ni] = *(const bf16x8*)&sB[cur][(r * 8 + c) * 8];
      }
#pragma unroll
      for (int mi = 0; mi < 4; ++mi)
#pragma unroll
        for (int ni = 0; ni < 4; ++ni)
          acc[mi][ni] = __builtin_amdgcn_mfma_f32_16x16x32_bf16(
              af[mi], bf_[ni], acc[mi][ni], 0, 0, 0);
    }
    __syncthreads();
    cur ^= 1;
  }

#pragma unroll
  for (int mi = 0; mi < 4; ++mi)
#pragma unroll
    for (int ni = 0; ni < 4; ++ni)
#pragma unroll
      for (int r = 0; r < 4; ++r) {
        int row = wm + mi * 16 + q * 4 + r;
        if (m_base + row < cnt) {
          int col = n_base + wn + ni * 16 + l15;
          float v = acc[mi][ni][r] * sW[row];
          ybuf[(size_t)(off + m_base + row) * H_DIM + col] = (bf16_t)v;
        }
      }
}

// ---------------- Legacy fallback GEMMs (ws too small) ---------------------
#define BM 64
#define BN 64
#define BK 32
#define LDK 40

__global__ __launch_bounds__(256) void gateup_kernel(
    const float* __restrict__ x, const float* __restrict__ w_gate,
    const float* __restrict__ w_up, const int* __restrict__ counts,
    const int* __restrict__ offsets, const int* __restrict__ token_list,
    bf16_t* __restrict__ hbuf) {
  int e = blockIdx.z;
  int cnt = counts[e];
  int m_base = blockIdx.x * BM;
  if (m_base >= cnt) return;
  int n_base = blockIdx.y * BN;
  int off = offsets[e];

  __shared__ bf16_t sA[BM][LDK];
  __shared__ bf16_t sBg[BN][LDK];
  __shared__ bf16_t sBu[BN][LDK];
  __shared__ int sTok[BM];

  int tid = threadIdx.x;
  if (tid < BM) {
    int s = m_base + tid;
    sTok[tid] = (s < cnt) ? token_list[off + s] : -1;
  }
  __syncthreads();

  int lane = tid & 63;
  int wv = tid >> 6;
  int wm = (wv >> 1) * 32;
  int wn = (wv & 1) * 32;
  int l15 = lane & 15;
  int q = lane >> 4;

  floatx4 zero = {0.f, 0.f, 0.f, 0.f};
  floatx4 ag[2][2], au[2][2];
  for (int i = 0; i < 2; i++)
    for (int j = 0; j < 2; j++) { ag[i][j] = zero; au[i][j] = zero; }

  int ar = tid >> 2;
  int ac = (tid & 3) * 8;
  int bn = tid & 63;
  int bk = (tid >> 6) * 8;

  const float* wg_base = w_gate + (size_t)e * H_DIM * I_DIM + n_base + bn;
  const float* wu_base = w_up + (size_t)e * H_DIM * I_DIM + n_base + bn;

  for (int k0 = 0; k0 < H_DIM; k0 += BK) {
    {
      int tok = sTok[ar];
      float v[8];
      if (tok >= 0) {
        const float* src = x + (size_t)tok * H_DIM + k0 + ac;
        float4 f0 = ((const float4*)src)[0];
        float4 f1 = ((const float4*)src)[1];
        v[0] = f0.x; v[1] = f0.y; v[2] = f0.z; v[3] = f0.w;
        v[4] = f1.x; v[5] = f1.y; v[6] = f1.z; v[7] = f1.w;
      } else {
        for (int j = 0; j < 8; j++) v[j] = 0.f;
      }
      bf16x8 b;
      for (int j = 0; j < 8; j++) b[j] = (bf16_t)v[j];
      *(bf16x8*)&sA[ar][ac] = b;
    }
    {
      bf16x8 bg, bu;
      const float* pg = wg_base + (size_t)(k0 + bk) * I_DIM;
      const float* pu = wu_base + (size_t)(k0 + bk) * I_DIM;
#pragma unroll
      for (int j = 0; j < 8; j++) {
        bg[j] = (bf16_t)pg[(size_t)j * I_DIM];
        bu[j] = (bf16_t)pu[(size_t)j * I_DIM];
      }
      *(bf16x8*)&sBg[bn][bk] = bg;
      *(bf16x8*)&sBu[bn][bk] = bu;
    }
    __syncthreads();

    bf16x8 af[2], bgf[2], buf_[2];
#pragma unroll
    for (int mi = 0; mi < 2; mi++)
      af[mi] = *(bf16x8*)&sA[wm + mi * 16 + l15][q * 8];
#pragma unroll
    for (int ni = 0; ni < 2; ni++) {
      bgf[ni] = *(bf16x8*)&sBg[wn + ni * 16 + l15][q * 8];
      buf_[ni] = *(bf16x8*)&sBu[wn + ni * 16 + l15][q * 8];
    }
#pragma unroll
    for (int mi = 0; mi < 2; mi++)
#pragma unroll
      for (int ni = 0; ni < 2; ni++) {
        ag[mi][ni] = __builtin_amdgcn_mfma_f32_16x16x32_bf16(
            af[mi], bgf[ni], ag[mi][ni], 0, 0, 0);
        au[mi][ni] = __builtin_amdgcn_mfma_f32_16x16x32_bf16(
            af[mi], buf_[ni], au[mi][ni], 0, 0, 0);
      }
    __syncthreads();
  }

#pragma unroll
  for (int mi = 0; mi < 2; mi++)
#pragma unroll
    for (int ni = 0; ni < 2; ni++)
#pragma unroll
      for (int r = 0; r < 4; r++) {
        int row = wm + mi * 16 + q * 4 + r;
        int col = wn + ni * 16 + l15;
        if (m_base + row < cnt) {
          float g = ag[mi][ni][r];
          float u = au[mi][ni][r];
          float hv = g * (1.f / (1.f + __expf(-g))) * u;
          hbuf[(size_t)(off + m_base + row) * I_DIM + n_base + col] =
              (bf16_t)hv;
        }
      }
}

template <bool ATOMIC>
__global__ __launch_bounds__(256) void down_kernel(
    const bf16_t* __restrict__ hbuf, const float* __restrict__ w_down,
    const int* __restrict__ counts, const int* __restrict__ offsets,
    const float* __restrict__ slot_wt, const int* __restrict__ token_list,
    bf16_t* __restrict__ ybuf, float* __restrict__ out) {
  int e = blockIdx.z;
  int cnt = counts[e];
  int m_base = blockIdx.x * BM;
  if (m_base >= cnt) return;
  int n_base = blockIdx.y * BN;
  int off = offsets[e];

  __shared__ bf16_t sA[BM][LDK];
  __shared__ bf16_t sB[BN][LDK];
  __shared__ float sW[BM];
  __shared__ int sTok[BM];

  int tid = threadIdx.x;
  if (tid < BM) {
    int s = m_base + tid;
    bool v = (s < cnt);
    sW[tid] = v ? slot_wt[off + s] : 0.f;
    sTok[tid] = v ? token_list[off + s] : 0;
  }
  __syncthreads();

  int lane = tid & 63;
  int wv = tid >> 6;
  int wm = (wv >> 1) * 32;
  int wn = (wv & 1) * 32;
  int l15 = lane & 15;
  int q = lane >> 4;

  floatx4 zero = {0.f, 0.f, 0.f, 0.f};
  floatx4 acc[2][2];
  for (int i = 0; i < 2; i++)
    for (int j = 0; j < 2; j++) acc[i][j] = zero;

  int ar = tid >> 2;
  int ac = (tid & 3) * 8;
  int bn = tid & 63;
  int bk = (tid >> 6) * 8;

  const float* wd_base = w_down + (size_t)e * I_DIM * H_DIM + n_base + bn;

  for (int k0 = 0; k0 < I_DIM; k0 += BK) {
    {
      bf16x8 a;
      if (m_base + ar < cnt) {
        a = *(const bf16x8*)&hbuf[(size_t)(off + m_base + ar) * I_DIM + k0 + ac];
      } else {
        for (int j = 0; j < 8; j++) a[j] = (bf16_t)0.f;
      }
      *(bf16x8*)&sA[ar][ac] = a;
    }
    {
      bf16x8 b;
      const float* pd = wd_base + (size_t)(k0 + bk) * H_DIM;
#pragma unroll
      for (int j = 0; j < 8; j++) b[j] = (bf16_t)pd[(size_t)j * H_DIM];
      *(bf16x8*)&sB[bn][bk] = b;
    }
    __syncthreads();

    bf16x8 af[2], bf[2];
#pragma unroll
    for (int mi = 0; mi < 2; mi++)
      af[mi] = *(bf16x8*)&sA[wm + mi * 16 + l15][q * 8];
#pragma unroll
    for (int ni = 0; ni < 2; ni++)
      bf[ni] = *(bf16x8*)&sB[wn + ni * 16 + l15][q * 8];
#pragma unroll
    for (int mi = 0; mi < 2; mi++)
#pragma unroll
      for (int ni = 0; ni < 2; ni++)
        acc[mi][ni] = __builtin_amdgcn_mfma_f32_16x16x32_bf16(
            af[mi], bf[ni], acc[mi][ni], 0, 0, 0);
    __syncthreads();
  }

#pragma unroll
  for (int mi = 0; mi < 2; mi++)
#pragma unroll
    for (int ni = 0; ni < 2; ni++)
#pragma unroll
      for (int r = 0; r < 4; r++) {
        int row = wm + mi * 16 + q * 4 + r;
        int col = wn + ni * 16 + l15;
        if (m_base + row < cnt) {
          float v = acc[mi][ni][r] * sW[row];
          if (ATOMIC) {
            atomicAdd(&out[(size_t)sTok[row] * H_DIM + n_base + col], v);
          } else {
            ybuf[(size_t)(off + m_base + row) * H_DIM + n_base + col] =
                (bf16_t)v;
          }
        }
      }
}

__global__ __launch_bounds__(256) void gather_kernel(
    const bf16_t* __restrict__ ybuf, const int* __restrict__ slot_of,
    float* __restrict__ out) {
  int g = blockIdx.x * 256 + threadIdx.x;
  int t = g >> 7;
  int c = (g & 127) * 8;
  float acc[8];
#pragma unroll
  for (int j = 0; j < 8; j++) acc[j] = 0.f;
#pragma unroll
  for (int k = 0; k < K_TOP; k++) {
    int slot = slot_of[t * K_TOP + k];
    bf16x8 yv = *(const bf16x8*)&ybuf[(size_t)slot * H_DIM + c];
#pragma unroll
    for (int j = 0; j < 8; j++) acc[j] += (float)yv[j];
  }
  float4* o = (float4*)(out + (size_t)t * H_DIM + c);
  o[0] = make_float4(acc[0], acc[1], acc[2], acc[3]);
  o[1] = make_float4(acc[4], acc[5], acc[6], acc[7]);
}

extern "C" void kernel_launch(void* const* d_in, const int* in_sizes, int n_in,
                              void* d_out, int out_size, void* d_ws,
                              size_t ws_size, hipStream_t stream) {
  const float* x = (const float*)d_in[0];
  const float* gate_w = (const float*)d_in[1];
  const float* w_gate = (const float*)d_in[2];
  const float* w_up = (const float*)d_in[3];
  const float* w_down = (const float*)d_in[4];
  float* out = (float*)d_out;

  char* ws = (char*)d_ws;
  int* counts = (int*)(ws + 0);
  int* cursors = (int*)(ws + 128);
  int* offsets = (int*)(ws + 256);
  int* topk_idx = (int*)(ws + 512);
  float* topk_wt = (float*)(ws + 512 + 131072);
  int* slot_of = (int*)(ws + 512 + 2 * 131072);
  int* token_list = (int*)(ws + 512 + 3 * 131072);
  float* slot_wt = (float*)(ws + 512 + 4 * 131072);
  // tile map (fits in the gap below 1 MB)
  int* tile_e = (int*)(ws + 786432);
  int* tile_m = (int*)(ws + 786432 + 2048);
  int* n_tiles = (int*)(ws + 786432 + 4096);

  const size_t H_BASE = 1ull << 20;
  const size_t H_BYTES = (size_t)NSLOT * I_DIM * 2;          // 32 MB
  const size_t Y_BYTES = (size_t)NSLOT * H_DIM * 2;          // 64 MB
  const size_t X_BYTES = (size_t)T_TOK * H_DIM * 2;          // 16 MB
  const size_t W_BYTES = (size_t)E_NUM * H_DIM * I_DIM * 2;  // 32 MB each
  bf16_t* hbuf = (bf16_t*)(ws + H_BASE);
  bf16_t* ybuf = (bf16_t*)(ws + H_BASE + H_BYTES);
  bf16_t* xb = (bf16_t*)(ws + H_BASE + H_BYTES + Y_BYTES);
  bf16_t* wgb = (bf16_t*)(ws + H_BASE + H_BYTES + Y_BYTES + X_BYTES);
  bf16_t* wub = (bf16_t*)(ws + H_BASE + H_BYTES + Y_BYTES + X_BYTES + W_BYTES);
  bf16_t* wdb =
      (bf16_t*)(ws + H_BASE + H_BYTES + Y_BYTES + X_BYTES + 2 * W_BYTES);

  bool fast = ws_size >= H_BASE + H_BYTES + Y_BYTES + X_BYTES + 3 * W_BYTES;
  bool gather_path = ws_size >= H_BASE + H_BYTES + Y_BYTES;

  hipMemsetAsync(ws, 0, 512, stream);

  if (fast) {
    router_kernel<<<T_TOK, 256, 0, stream>>>(x, gate_w, counts, topk_idx,
                                             topk_wt, xb);
    conv_transpose<<<dim3(H_DIM / 64, I_DIM / 64, E_NUM), 256, 0, stream>>>(
        w_gate, wgb, H_DIM, I_DIM);
    conv_transpose<<<dim3(H_DIM / 64, I_DIM / 64, E_NUM), 256, 0, stream>>>(
        w_up, wub, H_DIM, I_DIM);
    conv_transpose<<<dim3(I_DIM / 64, H_DIM / 64, E_NUM), 256, 0, stream>>>(
        w_down, wdb, I_DIM, H_DIM);
    scan_kernel<<<1, 64, 0, stream>>>(counts, offsets, tile_e, tile_m,
                                      n_tiles);
    build_kernel<<<T_TOK / 256, 256, 0, stream>>>(
        topk_idx, topk_wt, offsets, cursors, token_list, slot_wt, slot_of);
    gateup_fast<<<dim3(MAX_TILES, I_DIM / GBN), 256, 0, stream>>>(
        xb, wgb, wub, counts, offsets, token_list, tile_e, tile_m, n_tiles,
        hbuf);
    down_fast<<<dim3(MAX_TILES, H_DIM / DBN), 256, 0, stream>>>(
        hbuf, wdb, counts, offsets, slot_wt, tile_e, tile_m, n_tiles, ybuf);
    gather_kernel<<<(T_TOK * (H_DIM / 8)) / 256, 256, 0, stream>>>(
        ybuf, slot_of, out);
  } else {
    router_kernel<<<T_TOK, 256, 0, stream>>>(x, gate_w, counts, topk_idx,
                                             topk_wt, nullptr);
    scan_kernel<<<1, 64, 0, stream>>>(counts, offsets, tile_e, tile_m,
                                      n_tiles);
    build_kernel<<<T_TOK / 256, 256, 0, stream>>>(
        topk_idx, topk_wt, offsets, cursors, token_list, slot_wt, slot_of);
    gateup_kernel<<<dim3(T_TOK / BM, I_DIM / BN, E_NUM), 256, 0, stream>>>(
        x, w_gate, w_up, counts, offsets, token_list, hbuf);
    if (gather_path) {
      down_kernel<false>
          <<<dim3(T_TOK / BM, H_DIM / BN, E_NUM), 256, 0, stream>>>(
              hbuf, w_down, counts, offsets, slot_wt, token_list, ybuf, out);
      gather_kernel<<<(T_TOK * (H_DIM / 8)) / 256, 256, 0, stream>>>(
          ybuf, slot_of, out);
    } else {
      hipMemsetAsync(out, 0, (size_t)out_size * sizeof(float), stream);
      down_kernel<true>
          <<<dim3(T_TOK / BM, H_DIM / BN, E_NUM), 256, 0, stream>>>(
              hbuf, w_down, counts, offsets, slot_wt, token_list, ybuf, out);
    }
  }
}

// Round 3
// 745.502 us; speedup vs baseline: 1.4078x; 1.0448x over previous
//
#include <hip/hip_runtime.h>
#include <hip/hip_bf16.h>

// Qwen3 MoE block: T=8192 tokens, H=1024, I=512, E=32, top-4.
// Fast path: router(+x->bf16) -> w->bf16 transpose -> scan(+tile map) ->
//   gateup GEMM (2-phase dbuf, global_load_lds, swizzled) -> down GEMM ->
//   gather.

#define T_TOK 8192
#define H_DIM 1024
#define I_DIM 512
#define E_NUM 32
#define K_TOP 4
#define NSLOT (T_TOK * K_TOP)
#define MAX_TILES 288  // NSLOT/128 + E_NUM

typedef __bf16 bf16_t;
typedef __bf16 bf16x8 __attribute__((ext_vector_type(8)));
typedef float floatx4 __attribute__((ext_vector_type(4)));

__device__ __forceinline__ void async_lds16(const void* g, void* l) {
  __builtin_amdgcn_global_load_lds(
      (const __attribute__((address_space(1))) void*)g,
      (__attribute__((address_space(3))) void*)l, 16, 0, 0);
}

// ---------------- Router: one block per token (also emits bf16 x) ----------
// Dot product: float4-vectorized. Top-k: wave-parallel shfl argmax (NO
// runtime-indexed arrays -> no scratch).
__global__ __launch_bounds__(256) void router_kernel(
    const float* __restrict__ x, const float* __restrict__ gate_w,
    int* __restrict__ counts, int* __restrict__ topk_idx,
    float* __restrict__ topk_wt, bf16_t* __restrict__ xb) {
  __shared__ float sx[H_DIM];
  __shared__ float slog[E_NUM];
  int t = blockIdx.x;
  const float* xr = x + (size_t)t * H_DIM;
  for (int i = threadIdx.x; i < H_DIM / 4; i += 256)
    ((float4*)sx)[i] = ((const float4*)xr)[i];
  __syncthreads();

  if (xb) {  // free bf16 conversion of x while the row is in LDS
    for (int i = threadIdx.x; i < H_DIM / 8; i += 256) {
      const float* s = sx + i * 8;
      bf16x8 b;
#pragma unroll
      for (int j = 0; j < 8; j++) b[j] = (bf16_t)s[j];
      *(bf16x8*)&xb[(size_t)t * H_DIM + i * 8] = b;
    }
  }

  int e = threadIdx.x >> 3;  // 32 experts x 8 threads
  int p = threadIdx.x & 7;
  const float4* gw4 = (const float4*)(gate_w + (size_t)e * H_DIM);
  float acc = 0.f;
#pragma unroll
  for (int i = 0; i < H_DIM / 32; i++) {  // 32 float4 iters per thread
    float4 g = gw4[p + 8 * i];
    float4 xv = *(const float4*)&sx[(p + 8 * i) * 4];
    acc += xv.x * g.x + xv.y * g.y + xv.z * g.z + xv.w * g.w;
  }
  acc += __shfl_xor(acc, 1);
  acc += __shfl_xor(acc, 2);
  acc += __shfl_xor(acc, 4);
  if (p == 0) slog[e] = acc;
  __syncthreads();

  if (threadIdx.x < 64) {  // first wave: parallel top-4 over 32 logits
    int lane = threadIdx.x;
    float myv = (lane < E_NUM) ? slog[lane] : -1e30f;
    float val[K_TOP];
    int idx[K_TOP];
#pragma unroll
    for (int k = 0; k < K_TOP; k++) {
      float bv = myv;
      int bi = lane;
#pragma unroll
      for (int d = 1; d < 64; d <<= 1) {
        float ov = __shfl_xor(bv, d);
        int oi = __shfl_xor(bi, d);
        if (ov > bv || (ov == bv && oi < bi)) { bv = ov; bi = oi; }
      }
      val[k] = bv;
      idx[k] = bi;
      if (lane == bi) myv = -1e30f;  // knock out winner, stay in registers
    }
    if (lane == 0) {
      // softmax denom cancels under top-k renorm
      float m = val[0], s = 0.f, w[K_TOP];
#pragma unroll
      for (int k = 0; k < K_TOP; k++) { w[k] = __expf(val[k] - m); s += w[k]; }
      float inv = 1.f / s;
#pragma unroll
      for (int k = 0; k < K_TOP; k++) {
        topk_idx[t * K_TOP + k] = idx[k];
        topk_wt[t * K_TOP + k] = w[k] * inv;
        atomicAdd(&counts[idx[k]], 1);
      }
    }
  }
}

// scan + tile map: tiles of 128 rows over each expert's slot range
__global__ void scan_kernel(const int* __restrict__ counts,
                            int* __restrict__ offsets,
                            int* __restrict__ tile_e,
                            int* __restrict__ tile_m,
                            int* __restrict__ n_tiles) {
  if (threadIdx.x == 0 && blockIdx.x == 0) {
    int acc = 0, nt = 0;
    for (int e = 0; e < E_NUM; e++) {
      offsets[e] = acc;
      int c = counts[e];
      for (int m = 0; m < c; m += 128) {
        tile_e[nt] = e;
        tile_m[nt] = m;
        nt++;
      }
      acc += c;
    }
    offsets[E_NUM] = acc;
    *n_tiles = nt;
  }
}

__global__ __launch_bounds__(256) void build_kernel(
    const int* __restrict__ topk_idx, const float* __restrict__ topk_wt,
    const int* __restrict__ offsets, int* __restrict__ cursors,
    int* __restrict__ token_list, float* __restrict__ slot_wt,
    int* __restrict__ slot_of) {
  int t = blockIdx.x * 256 + threadIdx.x;
  if (t >= T_TOK) return;
  for (int k = 0; k < K_TOP; k++) {
    int e = topk_idx[t * K_TOP + k];
    int pos = atomicAdd(&cursors[e], 1);
    int slot = offsets[e] + pos;
    token_list[slot] = t;
    slot_wt[slot] = topk_wt[t * K_TOP + k];
    slot_of[t * K_TOP + k] = slot;
  }
}

// ------- Weight conversion: [E][R][C] fp32 -> [E][C][R] bf16 (transpose) ---
__global__ __launch_bounds__(256) void conv_transpose(
    const float* __restrict__ in, bf16_t* __restrict__ out, int R, int C) {
  __shared__ bf16_t sT[64][72];
  int e = blockIdx.z;
  int r0 = blockIdx.x * 64;
  int c0 = blockIdx.y * 64;
  const float* src = in + ((size_t)e * R + r0) * C + c0;
  bf16_t* dst = out + ((size_t)e * C + c0) * R + r0;
  int tid = threadIdx.x;
#pragma unroll
  for (int it = 0; it < 4; ++it) {
    int idx = it * 256 + tid;
    int r = idx >> 4;
    int c4 = (idx & 15) * 4;
    float4 f = *(const float4*)&src[(size_t)r * C + c4];
    sT[c4 + 0][r] = (bf16_t)f.x;
    sT[c4 + 1][r] = (bf16_t)f.y;
    sT[c4 + 2][r] = (bf16_t)f.z;
    sT[c4 + 3][r] = (bf16_t)f.w;
  }
  __syncthreads();
#pragma unroll
  for (int it = 0; it < 2; ++it) {
    int idx = it * 256 + tid;
    int c = idx >> 3;
    int r8 = (idx & 7) * 8;
    bf16x8 b = *(const bf16x8*)&sT[c][r8];
    *(bf16x8*)&dst[(size_t)c * R + r8] = b;
  }
}

// ---------------- Fast GEMMs: 2-phase double-buffered pipeline -------------
// LDS tiles row-major [rows][BK=64 bf16] = 8 x 16B chunks per row.
// global_load_lds writes LINEAR; source chunk pre-swizzled c = c' ^ (row&7);
// ds_read applies the same XOR -> conflict-free b128 fragment reads.
// Pipeline: STAGE(buf^1, t+1) issued BEFORE compute(buf) -> the barrier's
// vmcnt(0) drain has the whole MFMA phase in flight behind it.
#define GBM 128
#define GBN 64
#define GBK 64
#define G_NSTEP (H_DIM / GBK)

__global__ __launch_bounds__(256) void gateup_fast(
    const bf16_t* __restrict__ xb, const bf16_t* __restrict__ wgb,
    const bf16_t* __restrict__ wub, const int* __restrict__ counts,
    const int* __restrict__ offsets, const int* __restrict__ token_list,
    const int* __restrict__ tile_e, const int* __restrict__ tile_m,
    const int* __restrict__ n_tiles, bf16_t* __restrict__ hbuf) {
  int xt = blockIdx.x;
  if (xt >= *n_tiles) return;
  int e = tile_e[xt];
  int m_base = tile_m[xt];
  int cnt = counts[e];
  int off = offsets[e];
  int n_base = blockIdx.y * GBN;

  __shared__ bf16_t sA[2][GBM * GBK];   // 2 x 16 KB
  __shared__ bf16_t sBg[2][GBN * GBK];  // 2 x 8 KB
  __shared__ bf16_t sBu[2][GBN * GBK];  // 2 x 8 KB
  __shared__ int sTok[GBM];

  int tid = threadIdx.x;
  if (tid < GBM) {
    int s = m_base + tid;
    sTok[tid] = (s < cnt) ? token_list[off + s] : 0;
  }
  __syncthreads();

  int lane = tid & 63;
  int wv = tid >> 6;
  int wm = (wv >> 1) * 64;
  int wn = (wv & 1) * 32;
  int l15 = lane & 15;
  int q = lane >> 4;

  const bf16_t* asrc[4];
#pragma unroll
  for (int it = 0; it < 4; ++it) {
    int f = it * 256 + tid;
    int r = f >> 3;
    int c = (f & 7) ^ (r & 7);
    asrc[it] = xb + (size_t)sTok[r] * H_DIM + c * 8;
  }
  const bf16_t *bgs[2], *bus[2];
#pragma unroll
  for (int it = 0; it < 2; ++it) {
    int f = it * 256 + tid;
    int n = f >> 3;
    int c = (f & 7) ^ (n & 7);
    size_t o = ((size_t)e * I_DIM + n_base + n) * H_DIM + c * 8;
    bgs[it] = wgb + o;
    bus[it] = wub + o;
  }

  floatx4 zero = {0.f, 0.f, 0.f, 0.f};
  floatx4 ag[4][2], au[4][2];
#pragma unroll
  for (int mi = 0; mi < 4; ++mi)
#pragma unroll
    for (int ni = 0; ni < 2; ++ni) { ag[mi][ni] = zero; au[mi][ni] = zero; }

  auto stage = [&](int buf, int k0) {
    char* a = (char*)sA[buf];
    char* g = (char*)sBg[buf];
    char* u = (char*)sBu[buf];
#pragma unroll
    for (int it = 0; it < 4; ++it)
      async_lds16(asrc[it] + k0, a + (it * 256 + wv * 64) * 16);
#pragma unroll
    for (int it = 0; it < 2; ++it) {
      async_lds16(bgs[it] + k0, g + (it * 256 + wv * 64) * 16);
      async_lds16(bus[it] + k0, u + (it * 256 + wv * 64) * 16);
    }
  };

  // prologue: tile 0 into buf 0
  stage(0, 0);
  __syncthreads();

  int cur = 0;
  for (int t = 0; t < G_NSTEP; ++t) {
    if (t + 1 < G_NSTEP) stage(cur ^ 1, (t + 1) * GBK);  // prefetch next

#pragma unroll
    for (int ks = 0; ks < 2; ++ks) {
      bf16x8 af[4], bg[2], bu[2];
#pragma unroll
      for (int mi = 0; mi < 4; ++mi) {
        int r = wm + mi * 16 + l15;
        int c = (ks * 4 + q) ^ (r & 7);
        af[mi] = *(const bf16x8*)&sA[cur][(r * 8 + c) * 8];
      }
#pragma unroll
      for (int ni = 0; ni < 2; ++ni) {
        int r = wn + ni * 16 + l15;
        int c = (ks * 4 + q) ^ (r & 7);
        bg[ni] = *(const bf16x8*)&sBg[cur][(r * 8 + c) * 8];
        bu[ni] = *(const bf16x8*)&sBu[cur][(r * 8 + c) * 8];
      }
#pragma unroll
      for (int mi = 0; mi < 4; ++mi)
#pragma unroll
        for (int ni = 0; ni < 2; ++ni) {
          ag[mi][ni] = __builtin_amdgcn_mfma_f32_16x16x32_bf16(
              af[mi], bg[ni], ag[mi][ni], 0, 0, 0);
          au[mi][ni] = __builtin_amdgcn_mfma_f32_16x16x32_bf16(
              af[mi], bu[ni], au[mi][ni], 0, 0, 0);
        }
    }
    __syncthreads();  // drains vmcnt(0): prefetched loads had compute in flight
    cur ^= 1;
  }

  // epilogue: h = silu(g)*u. C layout: col=lane&15, row=q*4+reg.
#pragma unroll
  for (int mi = 0; mi < 4; ++mi)
#pragma unroll
    for (int ni = 0; ni < 2; ++ni)
#pragma unroll
      for (int r = 0; r < 4; ++r) {
        int row = wm + mi * 16 + q * 4 + r;
        if (m_base + row < cnt) {
          int col = n_base + wn + ni * 16 + l15;
          float g = ag[mi][ni][r];
          float u = au[mi][ni][r];
          float hv = g * (1.f / (1.f + __expf(-g))) * u;
          hbuf[(size_t)(off + m_base + row) * I_DIM + col] = (bf16_t)hv;
        }
      }
}

#define DBM 128
#define DBN 128
#define DBK 64
#define D_NSTEP (I_DIM / DBK)

__global__ __launch_bounds__(256) void down_fast(
    const bf16_t* __restrict__ hbuf, const bf16_t* __restrict__ wdb,
    const int* __restrict__ counts, const int* __restrict__ offsets,
    const float* __restrict__ slot_wt, const int* __restrict__ tile_e,
    const int* __restrict__ tile_m, const int* __restrict__ n_tiles,
    bf16_t* __restrict__ ybuf) {
  int xt = blockIdx.x;
  if (xt >= *n_tiles) return;
  int e = tile_e[xt];
  int m_base = tile_m[xt];
  int cnt = counts[e];
  int off = offsets[e];
  int n_base = blockIdx.y * DBN;

  __shared__ bf16_t sA[2][DBM * DBK];  // 2 x 16 KB
  __shared__ bf16_t sB[2][DBN * DBK];  // 2 x 16 KB
  __shared__ float sW[DBM];

  int tid = threadIdx.x;
  if (tid < DBM) {
    int s = m_base + tid;
    sW[tid] = (s < cnt) ? slot_wt[off + s] : 0.f;
  }

  int lane = tid & 63;
  int wv = tid >> 6;
  int wm = (wv >> 1) * 64;
  int wn = (wv & 1) * 64;
  int l15 = lane & 15;
  int q = lane >> 4;

  const bf16_t* asrc[4];
  const bf16_t* bsrc[4];
#pragma unroll
  for (int it = 0; it < 4; ++it) {
    int f = it * 256 + tid;
    int r = f >> 3;
    int c = (f & 7) ^ (r & 7);
    asrc[it] = hbuf + (size_t)(off + m_base + r) * I_DIM + c * 8;
    bsrc[it] = wdb + ((size_t)e * H_DIM + n_base + r) * I_DIM + c * 8;
  }

  floatx4 zero = {0.f, 0.f, 0.f, 0.f};
  floatx4 acc[4][4];
#pragma unroll
  for (int mi = 0; mi < 4; ++mi)
#pragma unroll
    for (int ni = 0; ni < 4; ++ni) acc[mi][ni] = zero;

  auto stage = [&](int buf, int k0) {
    char* a = (char*)sA[buf];
    char* b = (char*)sB[buf];
#pragma unroll
    for (int it = 0; it < 4; ++it) {
      async_lds16(asrc[it] + k0, a + (it * 256 + wv * 64) * 16);
      async_lds16(bsrc[it] + k0, b + (it * 256 + wv * 64) * 16);
    }
  };

  stage(0, 0);
  __syncthreads();

  int cur = 0;
  for (int t = 0; t < D_NSTEP; ++t) {
    if (t + 1 < D_NSTEP) stage(cur ^ 1, (t + 1) * DBK);

#pragma unroll
    for (int ks = 0; ks < 2; ++ks) {
      bf16x8 af[4], bf_[4];
#pragma unroll
      for (int mi = 0; mi < 4; ++mi) {
        int r = wm + mi * 16 + l15;
        int c = (ks * 4 + q) ^ (r & 7);
        af[mi] = *(const bf16x8*)&sA[cur][(r * 8 + c) * 8];
      }
#pragma unroll
      for (int ni = 0; ni < 4; ++ni) {
        int r = wn + ni * 16 + l15;
        int c = (ks * 4 + q) ^ (r & 7);
        bf_[ni] = *(const bf16x8*)&sB[cur][(r * 8 + c) * 8];
      }
#pragma unroll
      for (int mi = 0; mi < 4; ++mi)
#pragma unroll
        for (int ni = 0; ni < 4; ++ni)
          acc[mi][ni] = __builtin_amdgcn_mfma_f32_16x16x32_bf16(
              af[mi], bf_[ni], acc[mi][ni], 0, 0, 0);
    }
    __syncthreads();
    cur ^= 1;
  }

#pragma unroll
  for (int mi = 0; mi < 4; ++mi)
#pragma unroll
    for (int ni = 0; ni < 4; ++ni)
#pragma unroll
      for (int r = 0; r < 4; ++r) {
        int row = wm + mi * 16 + q * 4 + r;
        if (m_base + row < cnt) {
          int col = n_base + wn + ni * 16 + l15;
          float v = acc[mi][ni][r] * sW[row];
          ybuf[(size_t)(off + m_base + row) * H_DIM + col] = (bf16_t)v;
        }
      }
}

// ---------------- Legacy fallback GEMMs (ws too small) ---------------------
#define BM 64
#define BN 64
#define BK 32
#define LDK 40

__global__ __launch_bounds__(256) void gateup_kernel(
    const float* __restrict__ x, const float* __restrict__ w_gate,
    const float* __restrict__ w_up, const int* __restrict__ counts,
    const int* __restrict__ offsets, const int* __restrict__ token_list,
    bf16_t* __restrict__ hbuf) {
  int e = blockIdx.z;
  int cnt = counts[e];
  int m_base = blockIdx.x * BM;
  if (m_base >= cnt) return;
  int n_base = blockIdx.y * BN;
  int off = offsets[e];

  __shared__ bf16_t sA[BM][LDK];
  __shared__ bf16_t sBg[BN][LDK];
  __shared__ bf16_t sBu[BN][LDK];
  __shared__ int sTok[BM];

  int tid = threadIdx.x;
  if (tid < BM) {
    int s = m_base + tid;
    sTok[tid] = (s < cnt) ? token_list[off + s] : -1;
  }
  __syncthreads();

  int lane = tid & 63;
  int wv = tid >> 6;
  int wm = (wv >> 1) * 32;
  int wn = (wv & 1) * 32;
  int l15 = lane & 15;
  int q = lane >> 4;

  floatx4 zero = {0.f, 0.f, 0.f, 0.f};
  floatx4 ag[2][2], au[2][2];
  for (int i = 0; i < 2; i++)
    for (int j = 0; j < 2; j++) { ag[i][j] = zero; au[i][j] = zero; }

  int ar = tid >> 2;
  int ac = (tid & 3) * 8;
  int bn = tid & 63;
  int bk = (tid >> 6) * 8;

  const float* wg_base = w_gate + (size_t)e * H_DIM * I_DIM + n_base + bn;
  const float* wu_base = w_up + (size_t)e * H_DIM * I_DIM + n_base + bn;

  for (int k0 = 0; k0 < H_DIM; k0 += BK) {
    {
      int tok = sTok[ar];
      float v[8];
      if (tok >= 0) {
        const float* src = x + (size_t)tok * H_DIM + k0 + ac;
        float4 f0 = ((const float4*)src)[0];
        float4 f1 = ((const float4*)src)[1];
        v[0] = f0.x; v[1] = f0.y; v[2] = f0.z; v[3] = f0.w;
        v[4] = f1.x; v[5] = f1.y; v[6] = f1.z; v[7] = f1.w;
      } else {
        for (int j = 0; j < 8; j++) v[j] = 0.f;
      }
      bf16x8 b;
      for (int j = 0; j < 8; j++) b[j] = (bf16_t)v[j];
      *(bf16x8*)&sA[ar][ac] = b;
    }
    {
      bf16x8 bg, bu;
      const float* pg = wg_base + (size_t)(k0 + bk) * I_DIM;
      const float* pu = wu_base + (size_t)(k0 + bk) * I_DIM;
#pragma unroll
      for (int j = 0; j < 8; j++) {
        bg[j] = (bf16_t)pg[(size_t)j * I_DIM];
        bu[j] = (bf16_t)pu[(size_t)j * I_DIM];
      }
      *(bf16x8*)&sBg[bn][bk] = bg;
      *(bf16x8*)&sBu[bn][bk] = bu;
    }
    __syncthreads();

    bf16x8 af[2], bgf[2], buf_[2];
#pragma unroll
    for (int mi = 0; mi < 2; mi++)
      af[mi] = *(bf16x8*)&sA[wm + mi * 16 + l15][q * 8];
#pragma unroll
    for (int ni = 0; ni < 2; ni++) {
      bgf[ni] = *(bf16x8*)&sBg[wn + ni * 16 + l15][q * 8];
      buf_[ni] = *(bf16x8*)&sBu[wn + ni * 16 + l15][q * 8];
    }
#pragma unroll
    for (int mi = 0; mi < 2; mi++)
#pragma unroll
      for (int ni = 0; ni < 2; ni++) {
        ag[mi][ni] = __builtin_amdgcn_mfma_f32_16x16x32_bf16(
            af[mi], bgf[ni], ag[mi][ni], 0, 0, 0);
        au[mi][ni] = __builtin_amdgcn_mfma_f32_16x16x32_bf16(
            af[mi], buf_[ni], au[mi][ni], 0, 0, 0);
      }
    __syncthreads();
  }

#pragma unroll
  for (int mi = 0; mi < 2; mi++)
#pragma unroll
    for (int ni = 0; ni < 2; ni++)
#pragma unroll
      for (int r = 0; r < 4; r++) {
        int row = wm + mi * 16 + q * 4 + r;
        int col = wn + ni * 16 + l15;
        if (m_base + row < cnt) {
          float g = ag[mi][ni][r];
          float u = au[mi][ni][r];
          float hv = g * (1.f / (1.f + __expf(-g))) * u;
          hbuf[(size_t)(off + m_base + row) * I_DIM + n_base + col] =
              (bf16_t)hv;
        }
      }
}

template <bool ATOMIC>
__global__ __launch_bounds__(256) void down_kernel(
    const bf16_t* __restrict__ hbuf, const float* __restrict__ w_down,
    const int* __restrict__ counts, const int* __restrict__ offsets,
    const float* __restrict__ slot_wt, const int* __restrict__ token_list,
    bf16_t* __restrict__ ybuf, float* __restrict__ out) {
  int e = blockIdx.z;
  int cnt = counts[e];
  int m_base = blockIdx.x * BM;
  if (m_base >= cnt) return;
  int n_base = blockIdx.y * BN;
  int off = offsets[e];

  __shared__ bf16_t sA[BM][LDK];
  __shared__ bf16_t sB[BN][LDK];
  __shared__ float sW[BM];
  __shared__ int sTok[BM];

  int tid = threadIdx.x;
  if (tid < BM) {
    int s = m_base + tid;
    bool v = (s < cnt);
    sW[tid] = v ? slot_wt[off + s] : 0.f;
    sTok[tid] = v ? token_list[off + s] : 0;
  }
  __syncthreads();

  int lane = tid & 63;
  int wv = tid >> 6;
  int wm = (wv >> 1) * 32;
  int wn = (wv & 1) * 32;
  int l15 = lane & 15;
  int q = lane >> 4;

  floatx4 zero = {0.f, 0.f, 0.f, 0.f};
  floatx4 acc[2][2];
  for (int i = 0; i < 2; i++)
    for (int j = 0; j < 2; j++) acc[i][j] = zero;

  int ar = tid >> 2;
  int ac = (tid & 3) * 8;
  int bn = tid & 63;
  int bk = (tid >> 6) * 8;

  const float* wd_base = w_down + (size_t)e * I_DIM * H_DIM + n_base + bn;

  for (int k0 = 0; k0 < I_DIM; k0 += BK) {
    {
      bf16x8 a;
      if (m_base + ar < cnt) {
        a = *(const bf16x8*)&hbuf[(size_t)(off + m_base + ar) * I_DIM + k0 + ac];
      } else {
        for (int j = 0; j < 8; j++) a[j] = (bf16_t)0.f;
      }
      *(bf16x8*)&sA[ar][ac] = a;
    }
    {
      bf16x8 b;
      const float* pd = wd_base + (size_t)(k0 + bk) * H_DIM;
#pragma unroll
      for (int j = 0; j < 8; j++) b[j] = (bf16_t)pd[(size_t)j * H_DIM];
      *(bf16x8*)&sB[bn][bk] = b;
    }
    __syncthreads();

    bf16x8 af[2], bf[2];
#pragma unroll
    for (int mi = 0; mi < 2; mi++)
      af[mi] = *(bf16x8*)&sA[wm + mi * 16 + l15][q * 8];
#pragma unroll
    for (int ni = 0; ni < 2; ni++)
      bf[ni] = *(bf16x8*)&sB[wn + ni * 16 + l15][q * 8];
#pragma unroll
    for (int mi = 0; mi < 2; mi++)
#pragma unroll
      for (int ni = 0; ni < 2; ni++)
        acc[mi][ni] = __builtin_amdgcn_mfma_f32_16x16x32_bf16(
            af[mi], bf[ni], acc[mi][ni], 0, 0, 0);
    __syncthreads();
  }

#pragma unroll
  for (int mi = 0; mi < 2; mi++)
#pragma unroll
    for (int ni = 0; ni < 2; ni++)
#pragma unroll
      for (int r = 0; r < 4; r++) {
        int row = wm + mi * 16 + q * 4 + r;
        int col = wn + ni * 16 + l15;
        if (m_base + row < cnt) {
          float v = acc[mi][ni][r] * sW[row];
          if (ATOMIC) {
            atomicAdd(&out[(size_t)sTok[row] * H_DIM + n_base + col], v);
          } else {
            ybuf[(size_t)(off + m_base + row) * H_DIM + n_base + col] =
                (bf16_t)v;
          }
        }
      }
}

__global__ __launch_bounds__(256) void gather_kernel(
    const bf16_t* __restrict__ ybuf, const int* __restrict__ slot_of,
    float* __restrict__ out) {
  int g = blockIdx.x * 256 + threadIdx.x;
  int t = g >> 7;
  int c = (g & 127) * 8;
  float acc[8];
#pragma unroll
  for (int j = 0; j < 8; j++) acc[j] = 0.f;
#pragma unroll
  for (int k = 0; k < K_TOP; k++) {
    int slot = slot_of[t * K_TOP + k];
    bf16x8 yv = *(const bf16x8*)&ybuf[(size_t)slot * H_DIM + c];
#pragma unroll
    for (int j = 0; j < 8; j++) acc[j] += (float)yv[j];
  }
  float4* o = (float4*)(out + (size_t)t * H_DIM + c);
  o[0] = make_float4(acc[0], acc[1], acc[2], acc[3]);
  o[1] = make_float4(acc[4], acc[5], acc[6], acc[7]);
}

extern "C" void kernel_launch(void* const* d_in, const int* in_sizes, int n_in,
                              void* d_out, int out_size, void* d_ws,
                              size_t ws_size, hipStream_t stream) {
  const float* x = (const float*)d_in[0];
  const float* gate_w = (const float*)d_in[1];
  const float* w_gate = (const float*)d_in[2];
  const float* w_up = (const float*)d_in[3];
  const float* w_down = (const float*)d_in[4];
  float* out = (float*)d_out;

  char* ws = (char*)d_ws;
  int* counts = (int*)(ws + 0);
  int* cursors = (int*)(ws + 128);
  int* offsets = (int*)(ws + 256);
  int* topk_idx = (int*)(ws + 512);
  float* topk_wt = (float*)(ws + 512 + 131072);
  int* slot_of = (int*)(ws + 512 + 2 * 131072);
  int* token_list = (int*)(ws + 512 + 3 * 131072);
  float* slot_wt = (float*)(ws + 512 + 4 * 131072);
  // tile map (fits in the gap below 1 MB)
  int* tile_e = (int*)(ws + 786432);
  int* tile_m = (int*)(ws + 786432 + 2048);
  int* n_tiles = (int*)(ws + 786432 + 4096);

  const size_t H_BASE = 1ull << 20;
  const size_t H_BYTES = (size_t)NSLOT * I_DIM * 2;          // 32 MB
  const size_t Y_BYTES = (size_t)NSLOT * H_DIM * 2;          // 64 MB
  const size_t X_BYTES = (size_t)T_TOK * H_DIM * 2;          // 16 MB
  const size_t W_BYTES = (size_t)E_NUM * H_DIM * I_DIM * 2;  // 32 MB each
  bf16_t* hbuf = (bf16_t*)(ws + H_BASE);
  bf16_t* ybuf = (bf16_t*)(ws + H_BASE + H_BYTES);
  bf16_t* xb = (bf16_t*)(ws + H_BASE + H_BYTES + Y_BYTES);
  bf16_t* wgb = (bf16_t*)(ws + H_BASE + H_BYTES + Y_BYTES + X_BYTES);
  bf16_t* wub = (bf16_t*)(ws + H_BASE + H_BYTES + Y_BYTES + X_BYTES + W_BYTES);
  bf16_t* wdb =
      (bf16_t*)(ws + H_BASE + H_BYTES + Y_BYTES + X_BYTES + 2 * W_BYTES);

  bool fast = ws_size >= H_BASE + H_BYTES + Y_BYTES + X_BYTES + 3 * W_BYTES;
  bool gather_path = ws_size >= H_BASE + H_BYTES + Y_BYTES;

  hipMemsetAsync(ws, 0, 512, stream);

  if (fast) {
    router_kernel<<<T_TOK, 256, 0, stream>>>(x, gate_w, counts, topk_idx,
                                             topk_wt, xb);
    conv_transpose<<<dim3(H_DIM / 64, I_DIM / 64, E_NUM), 256, 0, stream>>>(
        w_gate, wgb, H_DIM, I_DIM);
    conv_transpose<<<dim3(H_DIM / 64, I_DIM / 64, E_NUM), 256, 0, stream>>>(
        w_up, wub, H_DIM, I_DIM);
    conv_transpose<<<dim3(I_DIM / 64, H_DIM / 64, E_NUM), 256, 0, stream>>>(
        w_down, wdb, I_DIM, H_DIM);
    scan_kernel<<<1, 64, 0, stream>>>(counts, offsets, tile_e, tile_m,
                                      n_tiles);
    build_kernel<<<T_TOK / 256, 256, 0, stream>>>(
        topk_idx, topk_wt, offsets, cursors, token_list, slot_wt, slot_of);
    gateup_fast<<<dim3(MAX_TILES, I_DIM / GBN), 256, 0, stream>>>(
        xb, wgb, wub, counts, offsets, token_list, tile_e, tile_m, n_tiles,
        hbuf);
    down_fast<<<dim3(MAX_TILES, H_DIM / DBN), 256, 0, stream>>>(
        hbuf, wdb, counts, offsets, slot_wt, tile_e, tile_m, n_tiles, ybuf);
    gather_kernel<<<(T_TOK * (H_DIM / 8)) / 256, 256, 0, stream>>>(
        ybuf, slot_of, out);
  } else {
    router_kernel<<<T_TOK, 256, 0, stream>>>(x, gate_w, counts, topk_idx,
                                             topk_wt, nullptr);
    scan_kernel<<<1, 64, 0, stream>>>(counts, offsets, tile_e, tile_m,
                                      n_tiles);
    build_kernel<<<T_TOK / 256, 256, 0, stream>>>(
        topk_idx, topk_wt, offsets, cursors, token_list, slot_wt, slot_of);
    gateup_kernel<<<dim3(T_TOK / BM, I_DIM / BN, E_NUM), 256, 0, stream>>>(
        x, w_gate, w_up, counts, offsets, token_list, hbuf);
    if (gather_path) {
      down_kernel<false>
          <<<dim3(T_TOK / BM, H_DIM / BN, E_NUM), 256, 0, stream>>>(
              hbuf, w_down, counts, offsets, slot_wt, token_list, ybuf, out);
      gather_kernel<<<(T_TOK * (H_DIM / 8)) / 256, 256, 0, stream>>>(
          ybuf, slot_of, out);
    } else {
      hipMemsetAsync(out, 0, (size_t)out_size * sizeof(float), stream);
      down_kernel<true>
          <<<dim3(T_TOK / BM, H_DIM / BN, E_NUM), 256, 0, stream>>>(
              hbuf, w_down, counts, offsets, slot_wt, token_list, ybuf, out);
    }
  }
}

// Round 6
// 531.894 us; speedup vs baseline: 1.9731x; 1.4016x over previous
//
#include <hip/hip_runtime.h>
#include <hip/hip_bf16.h>

// Qwen3 MoE block: T=8192 tokens, H=1024, I=512, E=32, top-4.
// Pipeline: router (8 tok/block, atomic-free) -> hist (LDS histogram) ->
//   scan (wave-parallel, per-block bases) -> build (LDS cursors) ->
//   gateup GEMM (2-phase dbuf, global_load_lds, swizzled) -> down GEMM ->
//   gather.  Weights converted to bf16 [n][k] once per launch.

#define T_TOK 8192
#define H_DIM 1024
#define I_DIM 512
#define E_NUM 32
#define K_TOP 4
#define NSLOT (T_TOK * K_TOP)
#define MAX_TILES 288   // NSLOT/128 + E_NUM
#define TPB 8           // router tokens per block
#define NBLK (T_TOK / 256)  // 32 histogram/build blocks

typedef __bf16 bf16_t;
typedef __bf16 bf16x8 __attribute__((ext_vector_type(8)));
typedef float floatx4 __attribute__((ext_vector_type(4)));

__device__ __forceinline__ void async_lds16(const void* g, void* l) {
  __builtin_amdgcn_global_load_lds(
      (const __attribute__((address_space(1))) void*)g,
      (__attribute__((address_space(3))) void*)l, 16, 0, 0);
}

// ---------------- Router: 8 tokens per block, NO global atomics ------------
// gate_w read once per 8 tokens (8x less L2 traffic). Top-k per 32-lane half.
__global__ __launch_bounds__(256) void router_kernel(
    const float* __restrict__ x, const float* __restrict__ gate_w,
    int* __restrict__ topk_idx, float* __restrict__ topk_wt,
    bf16_t* __restrict__ xb) {
  __shared__ __align__(16) float sx[TPB][H_DIM];  // 32 KB
  __shared__ float slog[TPB][E_NUM];
  int t0 = blockIdx.x * TPB;
  const float4* xr4 = (const float4*)(x + (size_t)t0 * H_DIM);
  float4* sx4 = (float4*)sx;
  for (int i = threadIdx.x; i < TPB * H_DIM / 4; i += 256)
    sx4[i] = xr4[i];
  __syncthreads();

  if (xb) {  // free bf16 conversion of the 8 rows while they sit in LDS
    for (int i = threadIdx.x; i < TPB * H_DIM / 8; i += 256) {
      const float* s = (const float*)sx + i * 8;
      bf16x8 b;
#pragma unroll
      for (int j = 0; j < 8; j++) b[j] = (bf16_t)s[j];
      *(bf16x8*)&xb[(size_t)t0 * H_DIM + i * 8] = b;
    }
  }

  // dot: thread = expert e (32) x part p (8); one gate_w float4 feeds 8 toks
  int e = threadIdx.x >> 3;
  int p = threadIdx.x & 7;
  const float4* gw4 = (const float4*)(gate_w + (size_t)e * H_DIM);
  float acc[TPB];
#pragma unroll
  for (int tt = 0; tt < TPB; tt++) acc[tt] = 0.f;
  for (int i = 0; i < H_DIM / 32; i++) {
    float4 g = gw4[p + 8 * i];
#pragma unroll
    for (int tt = 0; tt < TPB; tt++) {
      float4 xv = *(const float4*)&sx[tt][(p + 8 * i) * 4];
      acc[tt] += xv.x * g.x + xv.y * g.y + xv.z * g.z + xv.w * g.w;
    }
  }
#pragma unroll
  for (int tt = 0; tt < TPB; tt++) {
    float a = acc[tt];
    a += __shfl_xor(a, 1);
    a += __shfl_xor(a, 2);
    a += __shfl_xor(a, 4);
    if (p == 0) slog[tt][e] = a;
  }
  __syncthreads();

  // top-4: each 32-lane half owns one token; registers only, no scratch
  {
    int wv_ = threadIdx.x >> 6;
    int lane = threadIdx.x & 63;
    int h = lane >> 5;
    int l32 = lane & 31;
    int tt = wv_ * 2 + h;
    int t = t0 + tt;
    float myv = slog[tt][l32];
    float val[K_TOP];
    int idx[K_TOP];
#pragma unroll
    for (int k = 0; k < K_TOP; k++) {
      float bv = myv;
      int bi = l32;
#pragma unroll
      for (int d = 1; d < 32; d <<= 1) {  // stays within the 32-lane half
        float ov = __shfl_xor(bv, d);
        int oi = __shfl_xor(bi, d);
        if (ov > bv || (ov == bv && oi < bi)) { bv = ov; bi = oi; }
      }
      val[k] = bv;
      idx[k] = bi;
      if (l32 == bi) myv = -1e30f;
    }
    if (l32 == 0) {
      // softmax denom cancels under top-k renorm
      float m = val[0], s = 0.f, w[K_TOP];
#pragma unroll
      for (int k = 0; k < K_TOP; k++) { w[k] = __expf(val[k] - m); s += w[k]; }
      float inv = 1.f / s;
#pragma unroll
      for (int k = 0; k < K_TOP; k++) {
        topk_idx[t * K_TOP + k] = idx[k];
        topk_wt[t * K_TOP + k] = w[k] * inv;
      }
    }
  }
}

// ---------------- Histogram: LDS counts, plain global stores ---------------
__global__ __launch_bounds__(256) void hist_kernel(
    const int* __restrict__ topk_idx, int* __restrict__ block_counts) {
  __shared__ int hc[E_NUM];
  int b = blockIdx.x;
  if (threadIdx.x < E_NUM) hc[threadIdx.x] = 0;
  __syncthreads();
  int t = b * 256 + threadIdx.x;
#pragma unroll
  for (int k = 0; k < K_TOP; k++) {
    int e = topk_idx[t * K_TOP + k] & (E_NUM - 1);  // hardened: always in-range
    atomicAdd(&hc[e], 1);                           // LDS atomic only
  }
  __syncthreads();
  if (threadIdx.x < E_NUM)
    block_counts[b * E_NUM + threadIdx.x] = hc[threadIdx.x];
}

// ---------------- Scan: one wave; offsets, per-block bases, tile map -------
__global__ void scan_kernel(const int* __restrict__ block_counts,
                            int* __restrict__ counts,
                            int* __restrict__ offsets,
                            int* __restrict__ block_base,
                            int* __restrict__ tile_e, int* __restrict__ tile_m,
                            int* __restrict__ n_tiles) {
  int lane = threadIdx.x;  // 64 threads, single wave
  int e = lane & 31;
  int run = 0;
  if (lane < E_NUM) {
    for (int b = 0; b < NBLK; b++) {
      block_base[b * E_NUM + e] = run;  // within-expert running base
      run += block_counts[b * E_NUM + e];
    }
    counts[e] = run;
  }
  // exclusive prefix over experts (Hillis-Steele within 32 lanes)
  int v = (lane < E_NUM) ? run : 0;
#pragma unroll
  for (int d = 1; d < 32; d <<= 1) {
    int o = __shfl_up(v, d);
    if ((lane & 31) >= d) v += o;
  }
  int excl = v - ((lane < E_NUM) ? run : 0);
  if (lane < E_NUM) {
    offsets[e] = excl;
    for (int b = 0; b < NBLK; b++) block_base[b * E_NUM + e] += excl;
  }
  if (lane == 31) offsets[E_NUM] = v;
  // tile map (serial on lane 0, counts passed via shfl)
  int nt = 0;
  for (int ee = 0; ee < E_NUM; ee++) {
    int ce = __shfl(run, ee);
    if (lane == 0) {
      for (int m = 0; m < ce && nt < MAX_TILES; m += 128) {
        tile_e[nt] = ee;
        tile_m[nt] = m;
        nt++;
      }
    }
  }
  if (lane == 0) *n_tiles = nt;
}

// ---------------- Build: LDS cursors + per-block bases, no global atomics --
__global__ __launch_bounds__(256) void build_kernel(
    const int* __restrict__ topk_idx, const float* __restrict__ topk_wt,
    const int* __restrict__ block_base, int* __restrict__ token_list,
    float* __restrict__ slot_wt, int* __restrict__ slot_of) {
  __shared__ int cur[E_NUM];
  int b = blockIdx.x;
  if (threadIdx.x < E_NUM) cur[threadIdx.x] = 0;
  __syncthreads();
  int t = b * 256 + threadIdx.x;
#pragma unroll
  for (int k = 0; k < K_TOP; k++) {
    int e = topk_idx[t * K_TOP + k] & (E_NUM - 1);  // hardened: always in-range
    int pos = atomicAdd(&cur[e], 1);                // LDS atomic
    int slot = block_base[b * E_NUM + e] + pos;
    token_list[slot] = t;
    slot_wt[slot] = topk_wt[t * K_TOP + k];
    slot_of[t * K_TOP + k] = slot;
  }
}

// ------- Weight conversion: [E][R][C] fp32 -> [E][C][R] bf16 (transpose) ---
__global__ __launch_bounds__(256) void conv_transpose(
    const float* __restrict__ in, bf16_t* __restrict__ out, int R, int C) {
  __shared__ bf16_t sT[64][72];
  int e = blockIdx.z;
  int r0 = blockIdx.x * 64;
  int c0 = blockIdx.y * 64;
  const float* src = in + ((size_t)e * R + r0) * C + c0;
  bf16_t* dst = out + ((size_t)e * C + c0) * R + r0;
  int tid = threadIdx.x;
#pragma unroll
  for (int it = 0; it < 4; ++it) {
    int idx = it * 256 + tid;
    int r = idx >> 4;
    int c4 = (idx & 15) * 4;
    float4 f = *(const float4*)&src[(size_t)r * C + c4];
    sT[c4 + 0][r] = (bf16_t)f.x;
    sT[c4 + 1][r] = (bf16_t)f.y;
    sT[c4 + 2][r] = (bf16_t)f.z;
    sT[c4 + 3][r] = (bf16_t)f.w;
  }
  __syncthreads();
#pragma unroll
  for (int it = 0; it < 2; ++it) {
    int idx = it * 256 + tid;
    int c = idx >> 3;
    int r8 = (idx & 7) * 8;
    bf16x8 b = *(const bf16x8*)&sT[c][r8];
    *(bf16x8*)&dst[(size_t)c * R + r8] = b;
  }
}

// ---------------- Fast GEMMs: 2-phase double-buffered pipeline -------------
// LDS tiles row-major [rows][BK=64 bf16] = 8 x 16B chunks per row.
// global_load_lds writes LINEAR; source chunk pre-swizzled c = c' ^ (row&7);
// ds_read applies the same XOR -> conflict-free b128 fragment reads.
// Pipeline: STAGE(buf^1, t+1) issued BEFORE compute(buf) -> the barrier's
// vmcnt(0) drain has the whole MFMA phase in flight behind it.
#define GBM 128
#define GBN 64
#define GBK 64
#define G_NSTEP (H_DIM / GBK)

__global__ __launch_bounds__(256) void gateup_fast(
    const bf16_t* __restrict__ xb, const bf16_t* __restrict__ wgb,
    const bf16_t* __restrict__ wub, const int* __restrict__ counts,
    const int* __restrict__ offsets, const int* __restrict__ token_list,
    const int* __restrict__ tile_e, const int* __restrict__ tile_m,
    const int* __restrict__ n_tiles, bf16_t* __restrict__ hbuf) {
  int xt = blockIdx.x;
  if (xt >= *n_tiles) return;
  int e = tile_e[xt];
  int m_base = tile_m[xt];
  int cnt = counts[e];
  int off = offsets[e];
  int n_base = blockIdx.y * GBN;

  __shared__ bf16_t sA[2][GBM * GBK];   // 2 x 16 KB
  __shared__ bf16_t sBg[2][GBN * GBK];  // 2 x 8 KB
  __shared__ bf16_t sBu[2][GBN * GBK];  // 2 x 8 KB
  __shared__ int sTok[GBM];

  int tid = threadIdx.x;
  if (tid < GBM) {
    int s = m_base + tid;
    sTok[tid] = (s < cnt) ? token_list[off + s] : 0;
  }
  __syncthreads();

  int lane = tid & 63;
  int wv = tid >> 6;
  int wm = (wv >> 1) * 64;
  int wn = (wv & 1) * 32;
  int l15 = lane & 15;
  int q = lane >> 4;

  const bf16_t* asrc[4];
#pragma unroll
  for (int it = 0; it < 4; ++it) {
    int f = it * 256 + tid;
    int r = f >> 3;
    int c = (f & 7) ^ (r & 7);
    asrc[it] = xb + (size_t)sTok[r] * H_DIM + c * 8;
  }
  const bf16_t *bgs[2], *bus[2];
#pragma unroll
  for (int it = 0; it < 2; ++it) {
    int f = it * 256 + tid;
    int n = f >> 3;
    int c = (f & 7) ^ (n & 7);
    size_t o = ((size_t)e * I_DIM + n_base + n) * H_DIM + c * 8;
    bgs[it] = wgb + o;
    bus[it] = wub + o;
  }

  floatx4 zero = {0.f, 0.f, 0.f, 0.f};
  floatx4 ag[4][2], au[4][2];
#pragma unroll
  for (int mi = 0; mi < 4; ++mi)
#pragma unroll
    for (int ni = 0; ni < 2; ++ni) { ag[mi][ni] = zero; au[mi][ni] = zero; }

  auto stage = [&](int buf, int k0) {
    char* a = (char*)sA[buf];
    char* g = (char*)sBg[buf];
    char* u = (char*)sBu[buf];
#pragma unroll
    for (int it = 0; it < 4; ++it)
      async_lds16(asrc[it] + k0, a + (it * 256 + wv * 64) * 16);
#pragma unroll
    for (int it = 0; it < 2; ++it) {
      async_lds16(bgs[it] + k0, g + (it * 256 + wv * 64) * 16);
      async_lds16(bus[it] + k0, u + (it * 256 + wv * 64) * 16);
    }
  };

  stage(0, 0);
  __syncthreads();

  int cur = 0;
  for (int t = 0; t < G_NSTEP; ++t) {
    if (t + 1 < G_NSTEP) stage(cur ^ 1, (t + 1) * GBK);  // prefetch next

#pragma unroll
    for (int ks = 0; ks < 2; ++ks) {
      bf16x8 af[4], bg[2], bu[2];
#pragma unroll
      for (int mi = 0; mi < 4; ++mi) {
        int r = wm + mi * 16 + l15;
        int c = (ks * 4 + q) ^ (r & 7);
        af[mi] = *(const bf16x8*)&sA[cur][(r * 8 + c) * 8];
      }
#pragma unroll
      for (int ni = 0; ni < 2; ++ni) {
        int r = wn + ni * 16 + l15;
        int c = (ks * 4 + q) ^ (r & 7);
        bg[ni] = *(const bf16x8*)&sBg[cur][(r * 8 + c) * 8];
        bu[ni] = *(const bf16x8*)&sBu[cur][(r * 8 + c) * 8];
      }
#pragma unroll
      for (int mi = 0; mi < 4; ++mi)
#pragma unroll
        for (int ni = 0; ni < 2; ++ni) {
          ag[mi][ni] = __builtin_amdgcn_mfma_f32_16x16x32_bf16(
              af[mi], bg[ni], ag[mi][ni], 0, 0, 0);
          au[mi][ni] = __builtin_amdgcn_mfma_f32_16x16x32_bf16(
              af[mi], bu[ni], au[mi][ni], 0, 0, 0);
        }
    }
    __syncthreads();  // drains vmcnt(0): prefetched loads had compute in flight
    cur ^= 1;
  }

  // epilogue: h = silu(g)*u. C layout: col=lane&15, row=q*4+reg.
#pragma unroll
  for (int mi = 0; mi < 4; ++mi)
#pragma unroll
    for (int ni = 0; ni < 2; ++ni)
#pragma unroll
      for (int r = 0; r < 4; ++r) {
        int row = wm + mi * 16 + q * 4 + r;
        if (m_base + row < cnt) {
          int col = n_base + wn + ni * 16 + l15;
          float g = ag[mi][ni][r];
          float u = au[mi][ni][r];
          float hv = g * (1.f / (1.f + __expf(-g))) * u;
          hbuf[(size_t)(off + m_base + row) * I_DIM + col] = (bf16_t)hv;
        }
      }
}

#define DBM 128
#define DBN 128
#define DBK 64
#define D_NSTEP (I_DIM / DBK)

__global__ __launch_bounds__(256) void down_fast(
    const bf16_t* __restrict__ hbuf, const bf16_t* __restrict__ wdb,
    const int* __restrict__ counts, const int* __restrict__ offsets,
    const float* __restrict__ slot_wt, const int* __restrict__ tile_e,
    const int* __restrict__ tile_m, const int* __restrict__ n_tiles,
    bf16_t* __restrict__ ybuf) {
  int xt = blockIdx.x;
  if (xt >= *n_tiles) return;
  int e = tile_e[xt];
  int m_base = tile_m[xt];
  int cnt = counts[e];
  int off = offsets[e];
  int n_base = blockIdx.y * DBN;

  __shared__ bf16_t sA[2][DBM * DBK];  // 2 x 16 KB
  __shared__ bf16_t sB[2][DBN * DBK];  // 2 x 16 KB
  __shared__ float sW[DBM];

  int tid = threadIdx.x;
  if (tid < DBM) {
    int s = m_base + tid;
    sW[tid] = (s < cnt) ? slot_wt[off + s] : 0.f;
  }

  int lane = tid & 63;
  int wv = tid >> 6;
  int wm = (wv >> 1) * 64;
  int wn = (wv & 1) * 64;
  int l15 = lane & 15;
  int q = lane >> 4;

  const bf16_t* asrc[4];
  const bf16_t* bsrc[4];
#pragma unroll
  for (int it = 0; it < 4; ++it) {
    int f = it * 256 + tid;
    int r = f >> 3;
    int c = (f & 7) ^ (r & 7);
    asrc[it] = hbuf + (size_t)(off + m_base + r) * I_DIM + c * 8;
    bsrc[it] = wdb + ((size_t)e * H_DIM + n_base + r) * I_DIM + c * 8;
  }

  floatx4 zero = {0.f, 0.f, 0.f, 0.f};
  floatx4 acc[4][4];
#pragma unroll
  for (int mi = 0; mi < 4; ++mi)
#pragma unroll
    for (int ni = 0; ni < 4; ++ni) acc[mi][ni] = zero;

  auto stage = [&](int buf, int k0) {
    char* a = (char*)sA[buf];
    char* b = (char*)sB[buf];
#pragma unroll
    for (int it = 0; it < 4; ++it) {
      async_lds16(asrc[it] + k0, a + (it * 256 + wv * 64) * 16);
      async_lds16(bsrc[it] + k0, b + (it * 256 + wv * 64) * 16);
    }
  };

  stage(0, 0);
  __syncthreads();

  int cur = 0;
  for (int t = 0; t < D_NSTEP; ++t) {
    if (t + 1 < D_NSTEP) stage(cur ^ 1, (t + 1) * DBK);

#pragma unroll
    for (int ks = 0; ks < 2; ++ks) {
      bf16x8 af[4], bf_[4];
#pragma unroll
      for (int mi = 0; mi < 4; ++mi) {
        int r = wm + mi * 16 + l15;
        int c = (ks * 4 + q) ^ (r & 7);
        af[mi] = *(const bf16x8*)&sA[cur][(r * 8 + c) * 8];
      }
#pragma unroll
      for (int ni = 0; ni < 4; ++ni) {
        int r = wn + ni * 16 + l15;
        int c = (ks * 4 + q) ^ (r & 7);
        bf_[ni] = *(const bf16x8*)&sB[cur][(r * 8 + c) * 8];
      }
#pragma unroll
      for (int mi = 0; mi < 4; ++mi)
#pragma unroll
        for (int ni = 0; ni < 4; ++ni)
          acc[mi][ni] = __builtin_amdgcn_mfma_f32_16x16x32_bf16(
              af[mi], bf_[ni], acc[mi][ni], 0, 0, 0);
    }
    __syncthreads();
    cur ^= 1;
  }

#pragma unroll
  for (int mi = 0; mi < 4; ++mi)
#pragma unroll
    for (int ni = 0; ni < 4; ++ni)
#pragma unroll
      for (int r = 0; r < 4; ++r) {
        int row = wm + mi * 16 + q * 4 + r;
        if (m_base + row < cnt) {
          int col = n_base + wn + ni * 16 + l15;
          float v = acc[mi][ni][r] * sW[row];
          ybuf[(size_t)(off + m_base + row) * H_DIM + col] = (bf16_t)v;
        }
      }
}

// ---------------- Legacy fallback GEMMs (ws too small) ---------------------
#define BM 64
#define BN 64
#define BK 32
#define LDK 40

__global__ __launch_bounds__(256) void gateup_kernel(
    const float* __restrict__ x, const float* __restrict__ w_gate,
    const float* __restrict__ w_up, const int* __restrict__ counts,
    const int* __restrict__ offsets, const int* __restrict__ token_list,
    bf16_t* __restrict__ hbuf) {
  int e = blockIdx.z;
  int cnt = counts[e];
  int m_base = blockIdx.x * BM;
  if (m_base >= cnt) return;
  int n_base = blockIdx.y * BN;
  int off = offsets[e];

  __shared__ bf16_t sA[BM][LDK];
  __shared__ bf16_t sBg[BN][LDK];
  __shared__ bf16_t sBu[BN][LDK];
  __shared__ int sTok[BM];

  int tid = threadIdx.x;
  if (tid < BM) {
    int s = m_base + tid;
    sTok[tid] = (s < cnt) ? token_list[off + s] : -1;
  }
  __syncthreads();

  int lane = tid & 63;
  int wv = tid >> 6;
  int wm = (wv >> 1) * 32;
  int wn = (wv & 1) * 32;
  int l15 = lane & 15;
  int q = lane >> 4;

  floatx4 zero = {0.f, 0.f, 0.f, 0.f};
  floatx4 ag[2][2], au[2][2];
  for (int i = 0; i < 2; i++)
    for (int j = 0; j < 2; j++) { ag[i][j] = zero; au[i][j] = zero; }

  int ar = tid >> 2;
  int ac = (tid & 3) * 8;
  int bn = tid & 63;
  int bk = (tid >> 6) * 8;

  const float* wg_base = w_gate + (size_t)e * H_DIM * I_DIM + n_base + bn;
  const float* wu_base = w_up + (size_t)e * H_DIM * I_DIM + n_base + bn;

  for (int k0 = 0; k0 < H_DIM; k0 += BK) {
    {
      int tok = sTok[ar];
      float v[8];
      if (tok >= 0) {
        const float* src = x + (size_t)tok * H_DIM + k0 + ac;
        float4 f0 = ((const float4*)src)[0];
        float4 f1 = ((const float4*)src)[1];
        v[0] = f0.x; v[1] = f0.y; v[2] = f0.z; v[3] = f0.w;
        v[4] = f1.x; v[5] = f1.y; v[6] = f1.z; v[7] = f1.w;
      } else {
        for (int j = 0; j < 8; j++) v[j] = 0.f;
      }
      bf16x8 b;
      for (int j = 0; j < 8; j++) b[j] = (bf16_t)v[j];
      *(bf16x8*)&sA[ar][ac] = b;
    }
    {
      bf16x8 bg, bu;
      const float* pg = wg_base + (size_t)(k0 + bk) * I_DIM;
      const float* pu = wu_base + (size_t)(k0 + bk) * I_DIM;
#pragma unroll
      for (int j = 0; j < 8; j++) {
        bg[j] = (bf16_t)pg[(size_t)j * I_DIM];
        bu[j] = (bf16_t)pu[(size_t)j * I_DIM];
      }
      *(bf16x8*)&sBg[bn][bk] = bg;
      *(bf16x8*)&sBu[bn][bk] = bu;
    }
    __syncthreads();

    bf16x8 af[2], bgf[2], buf_[2];
#pragma unroll
    for (int mi = 0; mi < 2; mi++)
      af[mi] = *(bf16x8*)&sA[wm + mi * 16 + l15][q * 8];
#pragma unroll
    for (int ni = 0; ni < 2; ni++) {
      bgf[ni] = *(bf16x8*)&sBg[wn + ni * 16 + l15][q * 8];
      buf_[ni] = *(bf16x8*)&sBu[wn + ni * 16 + l15][q * 8];
    }
#pragma unroll
    for (int mi = 0; mi < 2; mi++)
#pragma unroll
      for (int ni = 0; ni < 2; ni++) {
        ag[mi][ni] = __builtin_amdgcn_mfma_f32_16x16x32_bf16(
            af[mi], bgf[ni], ag[mi][ni], 0, 0, 0);
        au[mi][ni] = __builtin_amdgcn_mfma_f32_16x16x32_bf16(
            af[mi], buf_[ni], au[mi][ni], 0, 0, 0);
      }
    __syncthreads();
  }

#pragma unroll
  for (int mi = 0; mi < 2; mi++)
#pragma unroll
    for (int ni = 0; ni < 2; ni++)
#pragma unroll
      for (int r = 0; r < 4; r++) {
        int row = wm + mi * 16 + q * 4 + r;
        int col = wn + ni * 16 + l15;
        if (m_base + row < cnt) {
          float g = ag[mi][ni][r];
          float u = au[mi][ni][r];
          float hv = g * (1.f / (1.f + __expf(-g))) * u;
          hbuf[(size_t)(off + m_base + row) * I_DIM + n_base + col] =
              (bf16_t)hv;
        }
      }
}

template <bool ATOMIC>
__global__ __launch_bounds__(256) void down_kernel(
    const bf16_t* __restrict__ hbuf, const float* __restrict__ w_down,
    const int* __restrict__ counts, const int* __restrict__ offsets,
    const float* __restrict__ slot_wt, const int* __restrict__ token_list,
    bf16_t* __restrict__ ybuf, float* __restrict__ out) {
  int e = blockIdx.z;
  int cnt = counts[e];
  int m_base = blockIdx.x * BM;
  if (m_base >= cnt) return;
  int n_base = blockIdx.y * BN;
  int off = offsets[e];

  __shared__ bf16_t sA[BM][LDK];
  __shared__ bf16_t sB[BN][LDK];
  __shared__ float sW[BM];
  __shared__ int sTok[BM];

  int tid = threadIdx.x;
  if (tid < BM) {
    int s = m_base + tid;
    bool v = (s < cnt);
    sW[tid] = v ? slot_wt[off + s] : 0.f;
    sTok[tid] = v ? token_list[off + s] : 0;
  }
  __syncthreads();

  int lane = tid & 63;
  int wv = tid >> 6;
  int wm = (wv >> 1) * 32;
  int wn = (wv & 1) * 32;
  int l15 = lane & 15;
  int q = lane >> 4;

  floatx4 zero = {0.f, 0.f, 0.f, 0.f};
  floatx4 acc[2][2];
  for (int i = 0; i < 2; i++)
    for (int j = 0; j < 2; j++) acc[i][j] = zero;

  int ar = tid >> 2;
  int ac = (tid & 3) * 8;
  int bn = tid & 63;
  int bk = (tid >> 6) * 8;

  const float* wd_base = w_down + (size_t)e * I_DIM * H_DIM + n_base + bn;

  for (int k0 = 0; k0 < I_DIM; k0 += BK) {
    {
      bf16x8 a;
      if (m_base + ar < cnt) {
        a = *(const bf16x8*)&hbuf[(size_t)(off + m_base + ar) * I_DIM + k0 + ac];
      } else {
        for (int j = 0; j < 8; j++) a[j] = (bf16_t)0.f;
      }
      *(bf16x8*)&sA[ar][ac] = a;
    }
    {
      bf16x8 b;
      const float* pd = wd_base + (size_t)(k0 + bk) * H_DIM;
#pragma unroll
      for (int j = 0; j < 8; j++) b[j] = (bf16_t)pd[(size_t)j * H_DIM];
      *(bf16x8*)&sB[bn][bk] = b;
    }
    __syncthreads();

    bf16x8 af[2], bf[2];
#pragma unroll
    for (int mi = 0; mi < 2; mi++)
      af[mi] = *(bf16x8*)&sA[wm + mi * 16 + l15][q * 8];
#pragma unroll
    for (int ni = 0; ni < 2; ni++)
      bf[ni] = *(bf16x8*)&sB[wn + ni * 16 + l15][q * 8];
#pragma unroll
    for (int mi = 0; mi < 2; mi++)
#pragma unroll
      for (int ni = 0; ni < 2; ni++)
        acc[mi][ni] = __builtin_amdgcn_mfma_f32_16x16x32_bf16(
            af[mi], bf[ni], acc[mi][ni], 0, 0, 0);
    __syncthreads();
  }

#pragma unroll
  for (int mi = 0; mi < 2; mi++)
#pragma unroll
    for (int ni = 0; ni < 2; ni++)
#pragma unroll
      for (int r = 0; r < 4; r++) {
        int row = wm + mi * 16 + q * 4 + r;
        int col = wn + ni * 16 + l15;
        if (m_base + row < cnt) {
          float v = acc[mi][ni][r] * sW[row];
          if (ATOMIC) {
            atomicAdd(&out[(size_t)sTok[row] * H_DIM + n_base + col], v);
          } else {
            ybuf[(size_t)(off + m_base + row) * H_DIM + n_base + col] =
                (bf16_t)v;
          }
        }
      }
}

__global__ __launch_bounds__(256) void gather_kernel(
    const bf16_t* __restrict__ ybuf, const int* __restrict__ slot_of,
    float* __restrict__ out) {
  int g = blockIdx.x * 256 + threadIdx.x;
  int t = g >> 7;
  int c = (g & 127) * 8;
  float acc[8];
#pragma unroll
  for (int j = 0; j < 8; j++) acc[j] = 0.f;
#pragma unroll
  for (int k = 0; k < K_TOP; k++) {
    int slot = slot_of[t * K_TOP + k];
    bf16x8 yv = *(const bf16x8*)&ybuf[(size_t)slot * H_DIM + c];
#pragma unroll
    for (int j = 0; j < 8; j++) acc[j] += (float)yv[j];
  }
  float4* o = (float4*)(out + (size_t)t * H_DIM + c);
  o[0] = make_float4(acc[0], acc[1], acc[2], acc[3]);
  o[1] = make_float4(acc[4], acc[5], acc[6], acc[7]);
}

extern "C" void kernel_launch(void* const* d_in, const int* in_sizes, int n_in,
                              void* d_out, int out_size, void* d_ws,
                              size_t ws_size, hipStream_t stream) {
  const float* x = (const float*)d_in[0];
  const float* gate_w = (const float*)d_in[1];
  const float* w_gate = (const float*)d_in[2];
  const float* w_up = (const float*)d_in[3];
  const float* w_down = (const float*)d_in[4];
  float* out = (float*)d_out;

  char* ws = (char*)d_ws;
  int* counts = (int*)(ws + 0);
  int* offsets = (int*)(ws + 256);
  int* topk_idx = (int*)(ws + 512);
  float* topk_wt = (float*)(ws + 512 + 131072);
  int* slot_of = (int*)(ws + 512 + 2 * 131072);
  int* token_list = (int*)(ws + 512 + 3 * 131072);
  float* slot_wt = (float*)(ws + 512 + 4 * 131072);
  // tile map + block tables (below 1 MB)
  int* tile_e = (int*)(ws + 786432);
  int* tile_m = (int*)(ws + 786432 + 2048);
  int* n_tiles = (int*)(ws + 786432 + 4096);
  int* block_counts = (int*)(ws + 786432 + 8192);   // [NBLK][E_NUM]
  int* block_base = (int*)(ws + 786432 + 12288);    // [NBLK][E_NUM]

  const size_t H_BASE = 1ull << 20;
  const size_t H_BYTES = (size_t)NSLOT * I_DIM * 2;          // 32 MB
  const size_t Y_BYTES = (size_t)NSLOT * H_DIM * 2;          // 64 MB
  const size_t X_BYTES = (size_t)T_TOK * H_DIM * 2;          // 16 MB
  const size_t W_BYTES = (size_t)E_NUM * H_DIM * I_DIM * 2;  // 32 MB each
  bf16_t* hbuf = (bf16_t*)(ws + H_BASE);
  bf16_t* ybuf = (bf16_t*)(ws + H_BASE + H_BYTES);
  bf16_t* xb = (bf16_t*)(ws + H_BASE + H_BYTES + Y_BYTES);
  bf16_t* wgb = (bf16_t*)(ws + H_BASE + H_BYTES + Y_BYTES + X_BYTES);
  bf16_t* wub = (bf16_t*)(ws + H_BASE + H_BYTES + Y_BYTES + X_BYTES + W_BYTES);
  bf16_t* wdb =
      (bf16_t*)(ws + H_BASE + H_BYTES + Y_BYTES + X_BYTES + 2 * W_BYTES);

  bool fast = ws_size >= H_BASE + H_BYTES + Y_BYTES + X_BYTES + 3 * W_BYTES;
  bool gather_path = ws_size >= H_BASE + H_BYTES + Y_BYTES;

  hipMemsetAsync(ws, 0, 512, stream);

  // routing pipeline (atomic-free), shared by both paths
  router_kernel<<<T_TOK / TPB, 256, 0, stream>>>(x, gate_w, topk_idx, topk_wt,
                                                 fast ? xb : nullptr);
  hist_kernel<<<NBLK, 256, 0, stream>>>(topk_idx, block_counts);
  scan_kernel<<<1, 64, 0, stream>>>(block_counts, counts, offsets, block_base,
                                    tile_e, tile_m, n_tiles);
  build_kernel<<<NBLK, 256, 0, stream>>>(topk_idx, topk_wt, block_base,
                                         token_list, slot_wt, slot_of);

  if (fast) {
    conv_transpose<<<dim3(H_DIM / 64, I_DIM / 64, E_NUM), 256, 0, stream>>>(
        w_gate, wgb, H_DIM, I_DIM);
    conv_transpose<<<dim3(H_DIM / 64, I_DIM / 64, E_NUM), 256, 0, stream>>>(
        w_up, wub, H_DIM, I_DIM);
    conv_transpose<<<dim3(I_DIM / 64, H_DIM / 64, E_NUM), 256, 0, stream>>>(
        w_down, wdb, I_DIM, H_DIM);
    gateup_fast<<<dim3(MAX_TILES, I_DIM / GBN), 256, 0, stream>>>(
        xb, wgb, wub, counts, offsets, token_list, tile_e, tile_m, n_tiles,
        hbuf);
    down_fast<<<dim3(MAX_TILES, H_DIM / DBN), 256, 0, stream>>>(
        hbuf, wdb, counts, offsets, slot_wt, tile_e, tile_m, n_tiles, ybuf);
    gather_kernel<<<(T_TOK * (H_DIM / 8)) / 256, 256, 0, stream>>>(
        ybuf, slot_of, out);
  } else {
    gateup_kernel<<<dim3(T_TOK / BM, I_DIM / BN, E_NUM), 256, 0, stream>>>(
        x, w_gate, w_up, counts, offsets, token_list, hbuf);
    if (gather_path) {
      down_kernel<false>
          <<<dim3(T_TOK / BM, H_DIM / BN, E_NUM), 256, 0, stream>>>(
              hbuf, w_down, counts, offsets, slot_wt, token_list, ybuf, out);
      gather_kernel<<<(T_TOK * (H_DIM / 8)) / 256, 256, 0, stream>>>(
          ybuf, slot_of, out);
    } else {
      hipMemsetAsync(out, 0, (size_t)out_size * sizeof(float), stream);
      down_kernel<true>
          <<<dim3(T_TOK / BM, H_DIM / BN, E_NUM), 256, 0, stream>>>(
              hbuf, w_down, counts, offsets, slot_wt, token_list, ybuf, out);
    }
  }
}

// Round 7
// 493.035 us; speedup vs baseline: 2.1286x; 1.0788x over previous
//
#include <hip/hip_runtime.h>
#include <hip/hip_bf16.h>

// Qwen3 MoE block: T=8192 tokens, H=1024, I=512, E=32, top-4.
// Pipeline: router (8 tok/block, atomic-free) -> hist (LDS histogram) ->
//   scan (wave-parallel, per-block bases) -> build (LDS cursors) ->
//   conv (weights -> bf16 [n][k], one launch) ->
//   gateup GEMM (2-phase dbuf, global_load_lds, swizzled LDS, XCD-swizzled
//   grid) -> down GEMM -> gather.

#define T_TOK 8192
#define H_DIM 1024
#define I_DIM 512
#define E_NUM 32
#define K_TOP 4
#define NSLOT (T_TOK * K_TOP)
#define MAX_TILES 288   // NSLOT/128 + E_NUM
#define TPB 8           // router tokens per block
#define NBLK (T_TOK / 256)  // 32 histogram/build blocks

typedef __bf16 bf16_t;
typedef __bf16 bf16x8 __attribute__((ext_vector_type(8)));
typedef float floatx4 __attribute__((ext_vector_type(4)));

__device__ __forceinline__ void async_lds16(const void* g, void* l) {
  __builtin_amdgcn_global_load_lds(
      (const __attribute__((address_space(1))) void*)g,
      (__attribute__((address_space(3))) void*)l, 16, 0, 0);
}

// ---------------- Router: 8 tokens per block, NO global atomics ------------
__global__ __launch_bounds__(256) void router_kernel(
    const float* __restrict__ x, const float* __restrict__ gate_w,
    int* __restrict__ topk_idx, float* __restrict__ topk_wt,
    bf16_t* __restrict__ xb) {
  __shared__ __align__(16) float sx[TPB][H_DIM];  // 32 KB
  __shared__ float slog[TPB][E_NUM];
  int t0 = blockIdx.x * TPB;
  const float4* xr4 = (const float4*)(x + (size_t)t0 * H_DIM);
  float4* sx4 = (float4*)sx;
  for (int i = threadIdx.x; i < TPB * H_DIM / 4; i += 256)
    sx4[i] = xr4[i];
  __syncthreads();

  if (xb) {  // free bf16 conversion of the 8 rows while they sit in LDS
    for (int i = threadIdx.x; i < TPB * H_DIM / 8; i += 256) {
      const float* s = (const float*)sx + i * 8;
      bf16x8 b;
#pragma unroll
      for (int j = 0; j < 8; j++) b[j] = (bf16_t)s[j];
      *(bf16x8*)&xb[(size_t)t0 * H_DIM + i * 8] = b;
    }
  }

  // dot: thread = expert e (32) x part p (8); one gate_w float4 feeds 8 toks
  int e = threadIdx.x >> 3;
  int p = threadIdx.x & 7;
  const float4* gw4 = (const float4*)(gate_w + (size_t)e * H_DIM);
  float acc[TPB];
#pragma unroll
  for (int tt = 0; tt < TPB; tt++) acc[tt] = 0.f;
  for (int i = 0; i < H_DIM / 32; i++) {
    float4 g = gw4[p + 8 * i];
#pragma unroll
    for (int tt = 0; tt < TPB; tt++) {
      float4 xv = *(const float4*)&sx[tt][(p + 8 * i) * 4];
      acc[tt] += xv.x * g.x + xv.y * g.y + xv.z * g.z + xv.w * g.w;
    }
  }
#pragma unroll
  for (int tt = 0; tt < TPB; tt++) {
    float a = acc[tt];
    a += __shfl_xor(a, 1);
    a += __shfl_xor(a, 2);
    a += __shfl_xor(a, 4);
    if (p == 0) slog[tt][e] = a;
  }
  __syncthreads();

  // top-4: each 32-lane half owns one token; registers only, no scratch
  {
    int wv_ = threadIdx.x >> 6;
    int lane = threadIdx.x & 63;
    int h = lane >> 5;
    int l32 = lane & 31;
    int tt = wv_ * 2 + h;
    int t = t0 + tt;
    float myv = slog[tt][l32];
    float val[K_TOP];
    int idx[K_TOP];
#pragma unroll
    for (int k = 0; k < K_TOP; k++) {
      float bv = myv;
      int bi = l32;
#pragma unroll
      for (int d = 1; d < 32; d <<= 1) {  // stays within the 32-lane half
        float ov = __shfl_xor(bv, d);
        int oi = __shfl_xor(bi, d);
        if (ov > bv || (ov == bv && oi < bi)) { bv = ov; bi = oi; }
      }
      val[k] = bv;
      idx[k] = bi;
      if (l32 == bi) myv = -1e30f;
    }
    if (l32 == 0) {
      // softmax denom cancels under top-k renorm
      float m = val[0], s = 0.f, w[K_TOP];
#pragma unroll
      for (int k = 0; k < K_TOP; k++) { w[k] = __expf(val[k] - m); s += w[k]; }
      float inv = 1.f / s;
#pragma unroll
      for (int k = 0; k < K_TOP; k++) {
        topk_idx[t * K_TOP + k] = idx[k];
        topk_wt[t * K_TOP + k] = w[k] * inv;
      }
    }
  }
}

// ---------------- Histogram: LDS counts, plain global stores ---------------
__global__ __launch_bounds__(256) void hist_kernel(
    const int* __restrict__ topk_idx, int* __restrict__ block_counts) {
  __shared__ int hc[E_NUM];
  int b = blockIdx.x;
  if (threadIdx.x < E_NUM) hc[threadIdx.x] = 0;
  __syncthreads();
  int t = b * 256 + threadIdx.x;
#pragma unroll
  for (int k = 0; k < K_TOP; k++) {
    int e = topk_idx[t * K_TOP + k] & (E_NUM - 1);  // hardened: always in-range
    atomicAdd(&hc[e], 1);                           // LDS atomic only
  }
  __syncthreads();
  if (threadIdx.x < E_NUM)
    block_counts[b * E_NUM + threadIdx.x] = hc[threadIdx.x];
}

// ---------------- Scan: one wave; offsets, per-block bases, tile map -------
__global__ void scan_kernel(const int* __restrict__ block_counts,
                            int* __restrict__ counts,
                            int* __restrict__ offsets,
                            int* __restrict__ block_base,
                            int* __restrict__ tile_e, int* __restrict__ tile_m,
                            int* __restrict__ n_tiles) {
  int lane = threadIdx.x;  // 64 threads, single wave
  int e = lane & 31;
  int run = 0;
  if (lane < E_NUM) {
    for (int b = 0; b < NBLK; b++) {
      block_base[b * E_NUM + e] = run;  // within-expert running base
      run += block_counts[b * E_NUM + e];
    }
    counts[e] = run;
  }
  // exclusive prefix over experts (Hillis-Steele within 32 lanes)
  int v = (lane < E_NUM) ? run : 0;
#pragma unroll
  for (int d = 1; d < 32; d <<= 1) {
    int o = __shfl_up(v, d);
    if ((lane & 31) >= d) v += o;
  }
  int excl = v - ((lane < E_NUM) ? run : 0);
  if (lane < E_NUM) {
    offsets[e] = excl;
    for (int b = 0; b < NBLK; b++) block_base[b * E_NUM + e] += excl;
  }
  if (lane == 31) offsets[E_NUM] = v;
  // tile map (serial on lane 0, counts passed via shfl)
  int nt = 0;
  for (int ee = 0; ee < E_NUM; ee++) {
    int ce = __shfl(run, ee);
    if (lane == 0) {
      for (int m = 0; m < ce && nt < MAX_TILES; m += 128) {
        tile_e[nt] = ee;
        tile_m[nt] = m;
        nt++;
      }
    }
  }
  if (lane == 0) *n_tiles = nt;
}

// ---------------- Build: LDS cursors + per-block bases, no global atomics --
__global__ __launch_bounds__(256) void build_kernel(
    const int* __restrict__ topk_idx, const float* __restrict__ topk_wt,
    const int* __restrict__ block_base, int* __restrict__ token_list,
    float* __restrict__ slot_wt, int* __restrict__ slot_of) {
  __shared__ int cur[E_NUM];
  int b = blockIdx.x;
  if (threadIdx.x < E_NUM) cur[threadIdx.x] = 0;
  __syncthreads();
  int t = b * 256 + threadIdx.x;
#pragma unroll
  for (int k = 0; k < K_TOP; k++) {
    int e = topk_idx[t * K_TOP + k] & (E_NUM - 1);  // hardened: always in-range
    int pos = atomicAdd(&cur[e], 1);                // LDS atomic
    int slot = block_base[b * E_NUM + e] + pos;
    token_list[slot] = t;
    slot_wt[slot] = topk_wt[t * K_TOP + k];
    slot_of[t * K_TOP + k] = slot;
  }
}

// ------- Weight conversion: [E][R][C] fp32 -> [E][C][R] bf16 (transpose) ---
// One launch for all three weights: flat grid, 128 blocks per expert each.
__device__ __forceinline__ void conv_tile(const float* __restrict__ src,
                                          bf16_t* __restrict__ dst, int R,
                                          int C, int tid) {
  __shared__ bf16_t sT[64][72];
#pragma unroll
  for (int it = 0; it < 4; ++it) {
    int idx = it * 256 + tid;
    int r = idx >> 4;
    int c4 = (idx & 15) * 4;
    float4 f = *(const float4*)&src[(size_t)r * C + c4];
    sT[c4 + 0][r] = (bf16_t)f.x;
    sT[c4 + 1][r] = (bf16_t)f.y;
    sT[c4 + 2][r] = (bf16_t)f.z;
    sT[c4 + 3][r] = (bf16_t)f.w;
  }
  __syncthreads();
#pragma unroll
  for (int it = 0; it < 2; ++it) {
    int idx = it * 256 + tid;
    int c = idx >> 3;
    int r8 = (idx & 7) * 8;
    bf16x8 b = *(const bf16x8*)&sT[c][r8];
    *(bf16x8*)&dst[(size_t)c * R + r8] = b;
  }
}

__global__ __launch_bounds__(256) void conv_all(
    const float* __restrict__ w_gate, const float* __restrict__ w_up,
    const float* __restrict__ w_down, bf16_t* __restrict__ wgb,
    bf16_t* __restrict__ wub, bf16_t* __restrict__ wdb) {
  int w = blockIdx.x;          // 3 * 32 * 128 blocks
  int which = w >> 12;         // / 4096
  int rem = w & 4095;
  int e = rem >> 7;
  int t = rem & 127;
  int tid = threadIdx.x;
  if (which == 0) {
    int r0 = (t >> 3) * 64, c0 = (t & 7) * 64;  // R=1024, C=512
    conv_tile(w_gate + ((size_t)e * H_DIM + r0) * I_DIM + c0,
              wgb + ((size_t)e * I_DIM + c0) * H_DIM + r0, H_DIM, I_DIM, tid);
  } else if (which == 1) {
    int r0 = (t >> 3) * 64, c0 = (t & 7) * 64;
    conv_tile(w_up + ((size_t)e * H_DIM + r0) * I_DIM + c0,
              wub + ((size_t)e * I_DIM + c0) * H_DIM + r0, H_DIM, I_DIM, tid);
  } else {
    int r0 = (t & 7) * 64, c0 = (t >> 3) * 64;  // R=512, C=1024
    conv_tile(w_down + ((size_t)e * I_DIM + r0) * H_DIM + c0,
              wdb + ((size_t)e * H_DIM + c0) * I_DIM + r0, I_DIM, H_DIM, tid);
  }
}

// ---------------- Fast GEMMs: 2-phase double-buffered pipeline -------------
// LDS tiles row-major [rows][BK=64 bf16] = 8 x 16B chunks per row.
// global_load_lds writes LINEAR; source chunk pre-swizzled c = c' ^ (row&7);
// ds_read applies the same XOR -> conflict-free b128 fragment reads.
// Grid XCD-swizzle: flat = bx + 288*by dispatches round-robin over 8 XCDs;
// w = (flat&7)*288 + flat>>3 gives each XCD a contiguous ny-fastest run:
// the 8 ny-blocks of one xt (shared A-tile) and ~64 blocks of one expert
// (shared B-panel) co-locate on one XCD's L2.
#define GBM 128
#define GBN 64
#define GBK 64
#define G_NSTEP (H_DIM / GBK)

__global__ __launch_bounds__(256) void gateup_fast(
    const bf16_t* __restrict__ xb, const bf16_t* __restrict__ wgb,
    const bf16_t* __restrict__ wub, const int* __restrict__ counts,
    const int* __restrict__ offsets, const int* __restrict__ token_list,
    const int* __restrict__ tile_e, const int* __restrict__ tile_m,
    const int* __restrict__ n_tiles, bf16_t* __restrict__ hbuf) {
  int flat = blockIdx.x + MAX_TILES * blockIdx.y;  // dispatch-linear id
  int w = (flat & 7) * MAX_TILES + (flat >> 3);    // 2304 = 8*288, bijective
  int xt = w >> 3;
  int n_base = (w & 7) * GBN;
  if (xt >= *n_tiles) return;
  int e = tile_e[xt];
  int m_base = tile_m[xt];
  int cnt = counts[e];
  int off = offsets[e];

  __shared__ bf16_t sA[2][GBM * GBK];   // 2 x 16 KB
  __shared__ bf16_t sBg[2][GBN * GBK];  // 2 x 8 KB
  __shared__ bf16_t sBu[2][GBN * GBK];  // 2 x 8 KB
  __shared__ int sTok[GBM];

  int tid = threadIdx.x;
  if (tid < GBM) {
    int s = m_base + tid;
    sTok[tid] = (s < cnt) ? token_list[off + s] : 0;
  }
  __syncthreads();

  int lane = tid & 63;
  int wv = tid >> 6;
  int wm = (wv >> 1) * 64;
  int wn = (wv & 1) * 32;
  int l15 = lane & 15;
  int q = lane >> 4;

  const bf16_t* asrc[4];
#pragma unroll
  for (int it = 0; it < 4; ++it) {
    int f = it * 256 + tid;
    int r = f >> 3;
    int c = (f & 7) ^ (r & 7);
    asrc[it] = xb + (size_t)sTok[r] * H_DIM + c * 8;
  }
  const bf16_t *bgs[2], *bus[2];
#pragma unroll
  for (int it = 0; it < 2; ++it) {
    int f = it * 256 + tid;
    int n = f >> 3;
    int c = (f & 7) ^ (n & 7);
    size_t o = ((size_t)e * I_DIM + n_base + n) * H_DIM + c * 8;
    bgs[it] = wgb + o;
    bus[it] = wub + o;
  }

  floatx4 zero = {0.f, 0.f, 0.f, 0.f};
  floatx4 ag[4][2], au[4][2];
#pragma unroll
  for (int mi = 0; mi < 4; ++mi)
#pragma unroll
    for (int ni = 0; ni < 2; ++ni) { ag[mi][ni] = zero; au[mi][ni] = zero; }

  auto stage = [&](int buf, int k0) {
    char* a = (char*)sA[buf];
    char* g = (char*)sBg[buf];
    char* u = (char*)sBu[buf];
#pragma unroll
    for (int it = 0; it < 4; ++it)
      async_lds16(asrc[it] + k0, a + (it * 256 + wv * 64) * 16);
#pragma unroll
    for (int it = 0; it < 2; ++it) {
      async_lds16(bgs[it] + k0, g + (it * 256 + wv * 64) * 16);
      async_lds16(bus[it] + k0, u + (it * 256 + wv * 64) * 16);
    }
  };

  stage(0, 0);
  __syncthreads();

  int cur = 0;
  for (int t = 0; t < G_NSTEP; ++t) {
    if (t + 1 < G_NSTEP) stage(cur ^ 1, (t + 1) * GBK);  // prefetch next

#pragma unroll
    for (int ks = 0; ks < 2; ++ks) {
      bf16x8 af[4], bg[2], bu[2];
#pragma unroll
      for (int mi = 0; mi < 4; ++mi) {
        int r = wm + mi * 16 + l15;
        int c = (ks * 4 + q) ^ (r & 7);
        af[mi] = *(const bf16x8*)&sA[cur][(r * 8 + c) * 8];
      }
#pragma unroll
      for (int ni = 0; ni < 2; ++ni) {
        int r = wn + ni * 16 + l15;
        int c = (ks * 4 + q) ^ (r & 7);
        bg[ni] = *(const bf16x8*)&sBg[cur][(r * 8 + c) * 8];
        bu[ni] = *(const bf16x8*)&sBu[cur][(r * 8 + c) * 8];
      }
#pragma unroll
      for (int mi = 0; mi < 4; ++mi)
#pragma unroll
        for (int ni = 0; ni < 2; ++ni) {
          ag[mi][ni] = __builtin_amdgcn_mfma_f32_16x16x32_bf16(
              af[mi], bg[ni], ag[mi][ni], 0, 0, 0);
          au[mi][ni] = __builtin_amdgcn_mfma_f32_16x16x32_bf16(
              af[mi], bu[ni], au[mi][ni], 0, 0, 0);
        }
    }
    __syncthreads();  // drains vmcnt(0): prefetched loads had compute in flight
    cur ^= 1;
  }

  // epilogue: h = silu(g)*u. C layout: col=lane&15, row=q*4+reg.
#pragma unroll
  for (int mi = 0; mi < 4; ++mi)
#pragma unroll
    for (int ni = 0; ni < 2; ++ni)
#pragma unroll
      for (int r = 0; r < 4; ++r) {
        int row = wm + mi * 16 + q * 4 + r;
        if (m_base + row < cnt) {
          int col = n_base + wn + ni * 16 + l15;
          float g = ag[mi][ni][r];
          float u = au[mi][ni][r];
          float hv = g * (1.f / (1.f + __expf(-g))) * u;
          hbuf[(size_t)(off + m_base + row) * I_DIM + col] = (bf16_t)hv;
        }
      }
}

#define DBM 128
#define DBN 128
#define DBK 64
#define D_NSTEP (I_DIM / DBK)

__global__ __launch_bounds__(256) void down_fast(
    const bf16_t* __restrict__ hbuf, const bf16_t* __restrict__ wdb,
    const int* __restrict__ counts, const int* __restrict__ offsets,
    const float* __restrict__ slot_wt, const int* __restrict__ tile_e,
    const int* __restrict__ tile_m, const int* __restrict__ n_tiles,
    bf16_t* __restrict__ ybuf) {
  int flat = blockIdx.x + MAX_TILES * blockIdx.y;  // dispatch-linear id
  int w = (flat & 7) * MAX_TILES + (flat >> 3);    // 2304 = 8*288, bijective
  int xt = w >> 3;
  int n_base = (w & 7) * DBN;
  if (xt >= *n_tiles) return;
  int e = tile_e[xt];
  int m_base = tile_m[xt];
  int cnt = counts[e];
  int off = offsets[e];

  __shared__ bf16_t sA[2][DBM * DBK];  // 2 x 16 KB
  __shared__ bf16_t sB[2][DBN * DBK];  // 2 x 16 KB
  __shared__ float sW[DBM];

  int tid = threadIdx.x;
  if (tid < DBM) {
    int s = m_base + tid;
    sW[tid] = (s < cnt) ? slot_wt[off + s] : 0.f;
  }

  int lane = tid & 63;
  int wv = tid >> 6;
  int wm = (wv >> 1) * 64;
  int wn = (wv & 1) * 64;
  int l15 = lane & 15;
  int q = lane >> 4;

  const bf16_t* asrc[4];
  const bf16_t* bsrc[4];
#pragma unroll
  for (int it = 0; it < 4; ++it) {
    int f = it * 256 + tid;
    int r = f >> 3;
    int c = (f & 7) ^ (r & 7);
    asrc[it] = hbuf + (size_t)(off + m_base + r) * I_DIM + c * 8;
    bsrc[it] = wdb + ((size_t)e * H_DIM + n_base + r) * I_DIM + c * 8;
  }

  floatx4 zero = {0.f, 0.f, 0.f, 0.f};
  floatx4 acc[4][4];
#pragma unroll
  for (int mi = 0; mi < 4; ++mi)
#pragma unroll
    for (int ni = 0; ni < 4; ++ni) acc[mi][ni] = zero;

  auto stage = [&](int buf, int k0) {
    char* a = (char*)sA[buf];
    char* b = (char*)sB[buf];
#pragma unroll
    for (int it = 0; it < 4; ++it) {
      async_lds16(asrc[it] + k0, a + (it * 256 + wv * 64) * 16);
      async_lds16(bsrc[it] + k0, b + (it * 256 + wv * 64) * 16);
    }
  };

  stage(0, 0);
  __syncthreads();

  int cur = 0;
  for (int t = 0; t < D_NSTEP; ++t) {
    if (t + 1 < D_NSTEP) stage(cur ^ 1, (t + 1) * DBK);

#pragma unroll
    for (int ks = 0; ks < 2; ++ks) {
      bf16x8 af[4], bf_[4];
#pragma unroll
      for (int mi = 0; mi < 4; ++mi) {
        int r = wm + mi * 16 + l15;
        int c = (ks * 4 + q) ^ (r & 7);
        af[mi] = *(const bf16x8*)&sA[cur][(r * 8 + c) * 8];
      }
#pragma unroll
      for (int ni = 0; ni < 4; ++ni) {
        int r = wn + ni * 16 + l15;
        int c = (ks * 4 + q) ^ (r & 7);
        bf_[ni] = *(const bf16x8*)&sB[cur][(r * 8 + c) * 8];
      }
#pragma unroll
      for (int mi = 0; mi < 4; ++mi)
#pragma unroll
        for (int ni = 0; ni < 4; ++ni)
          acc[mi][ni] = __builtin_amdgcn_mfma_f32_16x16x32_bf16(
              af[mi], bf_[ni], acc[mi][ni], 0, 0, 0);
    }
    __syncthreads();
    cur ^= 1;
  }

#pragma unroll
  for (int mi = 0; mi < 4; ++mi)
#pragma unroll
    for (int ni = 0; ni < 4; ++ni)
#pragma unroll
      for (int r = 0; r < 4; ++r) {
        int row = wm + mi * 16 + q * 4 + r;
        if (m_base + row < cnt) {
          int col = n_base + wn + ni * 16 + l15;
          float v = acc[mi][ni][r] * sW[row];
          ybuf[(size_t)(off + m_base + row) * H_DIM + col] = (bf16_t)v;
        }
      }
}

// ---------------- Legacy fallback GEMMs (ws too small) ---------------------
#define BM 64
#define BN 64
#define BK 32
#define LDK 40

__global__ __launch_bounds__(256) void gateup_kernel(
    const float* __restrict__ x, const float* __restrict__ w_gate,
    const float* __restrict__ w_up, const int* __restrict__ counts,
    const int* __restrict__ offsets, const int* __restrict__ token_list,
    bf16_t* __restrict__ hbuf) {
  int e = blockIdx.z;
  int cnt = counts[e];
  int m_base = blockIdx.x * BM;
  if (m_base >= cnt) return;
  int n_base = blockIdx.y * BN;
  int off = offsets[e];

  __shared__ bf16_t sA[BM][LDK];
  __shared__ bf16_t sBg[BN][LDK];
  __shared__ bf16_t sBu[BN][LDK];
  __shared__ int sTok[BM];

  int tid = threadIdx.x;
  if (tid < BM) {
    int s = m_base + tid;
    sTok[tid] = (s < cnt) ? token_list[off + s] : -1;
  }
  __syncthreads();

  int lane = tid & 63;
  int wv = tid >> 6;
  int wm = (wv >> 1) * 32;
  int wn = (wv & 1) * 32;
  int l15 = lane & 15;
  int q = lane >> 4;

  floatx4 zero = {0.f, 0.f, 0.f, 0.f};
  floatx4 ag[2][2], au[2][2];
  for (int i = 0; i < 2; i++)
    for (int j = 0; j < 2; j++) { ag[i][j] = zero; au[i][j] = zero; }

  int ar = tid >> 2;
  int ac = (tid & 3) * 8;
  int bn = tid & 63;
  int bk = (tid >> 6) * 8;

  const float* wg_base = w_gate + (size_t)e * H_DIM * I_DIM + n_base + bn;
  const float* wu_base = w_up + (size_t)e * H_DIM * I_DIM + n_base + bn;

  for (int k0 = 0; k0 < H_DIM; k0 += BK) {
    {
      int tok = sTok[ar];
      float v[8];
      if (tok >= 0) {
        const float* src = x + (size_t)tok * H_DIM + k0 + ac;
        float4 f0 = ((const float4*)src)[0];
        float4 f1 = ((const float4*)src)[1];
        v[0] = f0.x; v[1] = f0.y; v[2] = f0.z; v[3] = f0.w;
        v[4] = f1.x; v[5] = f1.y; v[6] = f1.z; v[7] = f1.w;
      } else {
        for (int j = 0; j < 8; j++) v[j] = 0.f;
      }
      bf16x8 b;
      for (int j = 0; j < 8; j++) b[j] = (bf16_t)v[j];
      *(bf16x8*)&sA[ar][ac] = b;
    }
    {
      bf16x8 bg, bu;
      const float* pg = wg_base + (size_t)(k0 + bk) * I_DIM;
      const float* pu = wu_base + (size_t)(k0 + bk) * I_DIM;
#pragma unroll
      for (int j = 0; j < 8; j++) {
        bg[j] = (bf16_t)pg[(size_t)j * I_DIM];
        bu[j] = (bf16_t)pu[(size_t)j * I_DIM];
      }
      *(bf16x8*)&sBg[bn][bk] = bg;
      *(bf16x8*)&sBu[bn][bk] = bu;
    }
    __syncthreads();

    bf16x8 af[2], bgf[2], buf_[2];
#pragma unroll
    for (int mi = 0; mi < 2; mi++)
      af[mi] = *(bf16x8*)&sA[wm + mi * 16 + l15][q * 8];
#pragma unroll
    for (int ni = 0; ni < 2; ni++) {
      bgf[ni] = *(bf16x8*)&sBg[wn + ni * 16 + l15][q * 8];
      buf_[ni] = *(bf16x8*)&sBu[wn + ni * 16 + l15][q * 8];
    }
#pragma unroll
    for (int mi = 0; mi < 2; mi++)
#pragma unroll
      for (int ni = 0; ni < 2; ni++) {
        ag[mi][ni] = __builtin_amdgcn_mfma_f32_16x16x32_bf16(
            af[mi], bgf[ni], ag[mi][ni], 0, 0, 0);
        au[mi][ni] = __builtin_amdgcn_mfma_f32_16x16x32_bf16(
            af[mi], buf_[ni], au[mi][ni], 0, 0, 0);
      }
    __syncthreads();
  }

#pragma unroll
  for (int mi = 0; mi < 2; mi++)
#pragma unroll
    for (int ni = 0; ni < 2; ni++)
#pragma unroll
      for (int r = 0; r < 4; r++) {
        int row = wm + mi * 16 + q * 4 + r;
        int col = wn + ni * 16 + l15;
        if (m_base + row < cnt) {
          float g = ag[mi][ni][r];
          float u = au[mi][ni][r];
          float hv = g * (1.f / (1.f + __expf(-g))) * u;
          hbuf[(size_t)(off + m_base + row) * I_DIM + n_base + col] =
              (bf16_t)hv;
        }
      }
}

template <bool ATOMIC>
__global__ __launch_bounds__(256) void down_kernel(
    const bf16_t* __restrict__ hbuf, const float* __restrict__ w_down,
    const int* __restrict__ counts, const int* __restrict__ offsets,
    const float* __restrict__ slot_wt, const int* __restrict__ token_list,
    bf16_t* __restrict__ ybuf, float* __restrict__ out) {
  int e = blockIdx.z;
  int cnt = counts[e];
  int m_base = blockIdx.x * BM;
  if (m_base >= cnt) return;
  int n_base = blockIdx.y * BN;
  int off = offsets[e];

  __shared__ bf16_t sA[BM][LDK];
  __shared__ bf16_t sB[BN][LDK];
  __shared__ float sW[BM];
  __shared__ int sTok[BM];

  int tid = threadIdx.x;
  if (tid < BM) {
    int s = m_base + tid;
    bool v = (s < cnt);
    sW[tid] = v ? slot_wt[off + s] : 0.f;
    sTok[tid] = v ? token_list[off + s] : 0;
  }
  __syncthreads();

  int lane = tid & 63;
  int wv = tid >> 6;
  int wm = (wv >> 1) * 32;
  int wn = (wv & 1) * 32;
  int l15 = lane & 15;
  int q = lane >> 4;

  floatx4 zero = {0.f, 0.f, 0.f, 0.f};
  floatx4 acc[2][2];
  for (int i = 0; i < 2; i++)
    for (int j = 0; j < 2; j++) acc[i][j] = zero;

  int ar = tid >> 2;
  int ac = (tid & 3) * 8;
  int bn = tid & 63;
  int bk = (tid >> 6) * 8;

  const float* wd_base = w_down + (size_t)e * I_DIM * H_DIM + n_base + bn;

  for (int k0 = 0; k0 < I_DIM; k0 += BK) {
    {
      bf16x8 a;
      if (m_base + ar < cnt) {
        a = *(const bf16x8*)&hbuf[(size_t)(off + m_base + ar) * I_DIM + k0 + ac];
      } else {
        for (int j = 0; j < 8; j++) a[j] = (bf16_t)0.f;
      }
      *(bf16x8*)&sA[ar][ac] = a;
    }
    {
      bf16x8 b;
      const float* pd = wd_base + (size_t)(k0 + bk) * H_DIM;
#pragma unroll
      for (int j = 0; j < 8; j++) b[j] = (bf16_t)pd[(size_t)j * H_DIM];
      *(bf16x8*)&sB[bn][bk] = b;
    }
    __syncthreads();

    bf16x8 af[2], bf[2];
#pragma unroll
    for (int mi = 0; mi < 2; mi++)
      af[mi] = *(bf16x8*)&sA[wm + mi * 16 + l15][q * 8];
#pragma unroll
    for (int ni = 0; ni < 2; ni++)
      bf[ni] = *(bf16x8*)&sB[wn + ni * 16 + l15][q * 8];
#pragma unroll
    for (int mi = 0; mi < 2; mi++)
#pragma unroll
      for (int ni = 0; ni < 2; ni++)
        acc[mi][ni] = __builtin_amdgcn_mfma_f32_16x16x32_bf16(
            af[mi], bf[ni], acc[mi][ni], 0, 0, 0);
    __syncthreads();
  }

#pragma unroll
  for (int mi = 0; mi < 2; mi++)
#pragma unroll
    for (int ni = 0; ni < 2; ni++)
#pragma unroll
      for (int r = 0; r < 4; r++) {
        int row = wm + mi * 16 + q * 4 + r;
        int col = wn + ni * 16 + l15;
        if (m_base + row < cnt) {
          float v = acc[mi][ni][r] * sW[row];
          if (ATOMIC) {
            atomicAdd(&out[(size_t)sTok[row] * H_DIM + n_base + col], v);
          } else {
            ybuf[(size_t)(off + m_base + row) * H_DIM + n_base + col] =
                (bf16_t)v;
          }
        }
      }
}

__global__ __launch_bounds__(256) void gather_kernel(
    const bf16_t* __restrict__ ybuf, const int* __restrict__ slot_of,
    float* __restrict__ out) {
  int g = blockIdx.x * 256 + threadIdx.x;
  int t = g >> 7;
  int c = (g & 127) * 8;
  float acc[8];
#pragma unroll
  for (int j = 0; j < 8; j++) acc[j] = 0.f;
#pragma unroll
  for (int k = 0; k < K_TOP; k++) {
    int slot = slot_of[t * K_TOP + k];
    bf16x8 yv = *(const bf16x8*)&ybuf[(size_t)slot * H_DIM + c];
#pragma unroll
    for (int j = 0; j < 8; j++) acc[j] += (float)yv[j];
  }
  float4* o = (float4*)(out + (size_t)t * H_DIM + c);
  o[0] = make_float4(acc[0], acc[1], acc[2], acc[3]);
  o[1] = make_float4(acc[4], acc[5], acc[6], acc[7]);
}

extern "C" void kernel_launch(void* const* d_in, const int* in_sizes, int n_in,
                              void* d_out, int out_size, void* d_ws,
                              size_t ws_size, hipStream_t stream) {
  const float* x = (const float*)d_in[0];
  const float* gate_w = (const float*)d_in[1];
  const float* w_gate = (const float*)d_in[2];
  const float* w_up = (const float*)d_in[3];
  const float* w_down = (const float*)d_in[4];
  float* out = (float*)d_out;

  char* ws = (char*)d_ws;
  int* counts = (int*)(ws + 0);
  int* offsets = (int*)(ws + 256);
  int* topk_idx = (int*)(ws + 512);
  float* topk_wt = (float*)(ws + 512 + 131072);
  int* slot_of = (int*)(ws + 512 + 2 * 131072);
  int* token_list = (int*)(ws + 512 + 3 * 131072);
  float* slot_wt = (float*)(ws + 512 + 4 * 131072);
  // tile map + block tables (below 1 MB)
  int* tile_e = (int*)(ws + 786432);
  int* tile_m = (int*)(ws + 786432 + 2048);
  int* n_tiles = (int*)(ws + 786432 + 4096);
  int* block_counts = (int*)(ws + 786432 + 8192);   // [NBLK][E_NUM]
  int* block_base = (int*)(ws + 786432 + 12288);    // [NBLK][E_NUM]

  const size_t H_BASE = 1ull << 20;
  const size_t H_BYTES = (size_t)NSLOT * I_DIM * 2;          // 32 MB
  const size_t Y_BYTES = (size_t)NSLOT * H_DIM * 2;          // 64 MB
  const size_t X_BYTES = (size_t)T_TOK * H_DIM * 2;          // 16 MB
  const size_t W_BYTES = (size_t)E_NUM * H_DIM * I_DIM * 2;  // 32 MB each
  bf16_t* hbuf = (bf16_t*)(ws + H_BASE);
  bf16_t* ybuf = (bf16_t*)(ws + H_BASE + H_BYTES);
  bf16_t* xb = (bf16_t*)(ws + H_BASE + H_BYTES + Y_BYTES);
  bf16_t* wgb = (bf16_t*)(ws + H_BASE + H_BYTES + Y_BYTES + X_BYTES);
  bf16_t* wub = (bf16_t*)(ws + H_BASE + H_BYTES + Y_BYTES + X_BYTES + W_BYTES);
  bf16_t* wdb =
      (bf16_t*)(ws + H_BASE + H_BYTES + Y_BYTES + X_BYTES + 2 * W_BYTES);

  bool fast = ws_size >= H_BASE + H_BYTES + Y_BYTES + X_BYTES + 3 * W_BYTES;
  bool gather_path = ws_size >= H_BASE + H_BYTES + Y_BYTES;

  hipMemsetAsync(ws, 0, 512, stream);

  // routing pipeline (atomic-free), shared by both paths
  router_kernel<<<T_TOK / TPB, 256, 0, stream>>>(x, gate_w, topk_idx, topk_wt,
                                                 fast ? xb : nullptr);
  hist_kernel<<<NBLK, 256, 0, stream>>>(topk_idx, block_counts);
  scan_kernel<<<1, 64, 0, stream>>>(block_counts, counts, offsets, block_base,
                                    tile_e, tile_m, n_tiles);
  build_kernel<<<NBLK, 256, 0, stream>>>(topk_idx, topk_wt, block_base,
                                         token_list, slot_wt, slot_of);

  if (fast) {
    conv_all<<<3 * 4096, 256, 0, stream>>>(w_gate, w_up, w_down, wgb, wub,
                                           wdb);
    gateup_fast<<<dim3(MAX_TILES, I_DIM / GBN), 256, 0, stream>>>(
        xb, wgb, wub, counts, offsets, token_list, tile_e, tile_m, n_tiles,
        hbuf);
    down_fast<<<dim3(MAX_TILES, H_DIM / DBN), 256, 0, stream>>>(
        hbuf, wdb, counts, offsets, slot_wt, tile_e, tile_m, n_tiles, ybuf);
    gather_kernel<<<(T_TOK * (H_DIM / 8)) / 256, 256, 0, stream>>>(
        ybuf, slot_of, out);
  } else {
    gateup_kernel<<<dim3(T_TOK / BM, I_DIM / BN, E_NUM), 256, 0, stream>>>(
        x, w_gate, w_up, counts, offsets, token_list, hbuf);
    if (gather_path) {
      down_kernel<false>
          <<<dim3(T_TOK / BM, H_DIM / BN, E_NUM), 256, 0, stream>>>(
              hbuf, w_down, counts, offsets, slot_wt, token_list, ybuf, out);
      gather_kernel<<<(T_TOK * (H_DIM / 8)) / 256, 256, 0, stream>>>(
          ybuf, slot_of, out);
    } else {
      hipMemsetAsync(out, 0, (size_t)out_size * sizeof(float), stream);
      down_kernel<true>
          <<<dim3(T_TOK / BM, H_DIM / BN, E_NUM), 256, 0, stream>>>(
              hbuf, w_down, counts, offsets, slot_wt, token_list, ybuf, out);
    }
  }
}